// Round 1
// baseline (2233.651 us; speedup 1.0000x reference)
//
#include <hip/hip_runtime.h>

#define B_ 2
#define N_ 2048
#define K_ 256
#define D_ 768
#define H_ 256
#define L_ 64
#define BK_ (B_*K_)

__device__ __forceinline__ float sigm(float x) { return 1.0f / (1.0f + __expf(-x)); }
__device__ __forceinline__ void st4(float* p, float4 v) { p[0]=v.x; p[1]=v.y; p[2]=v.z; p[3]=v.w; }

// ---------- left/right projections: out[r,n] = U[r,:]·W[n,:] + bias[n] ----------
// grid (BK/64, H/64, 2), block 256. side=z: 0->left, 1->right.
__global__ __launch_bounds__(256) void lr_kernel(
    const float* __restrict__ U,
    const float* __restrict__ lw, const float* __restrict__ lb,
    const float* __restrict__ rw, const float* __restrict__ rb,
    float* __restrict__ outL, float* __restrict__ outR)
{
    const int side = blockIdx.z;
    const float* __restrict__ W = side ? rw : lw;
    const float* __restrict__ bias = side ? rb : lb;
    float* __restrict__ out = side ? outR : outL;
    const int r0 = blockIdx.x * 64, n0 = blockIdx.y * 64;
    const int tid = threadIdx.x;
    const int lrow = tid >> 2, lcg = (tid & 3) * 8;
    const int tr = tid >> 4, tc = tid & 15;
    __shared__ float sA[64][33];
    __shared__ float sW[64][33];
    float acc[4][4] = {};
    for (int k0 = 0; k0 < D_; k0 += 32) {
        float4 a0 = *(const float4*)&U[(size_t)(r0+lrow)*D_ + k0 + lcg];
        float4 a1 = *(const float4*)&U[(size_t)(r0+lrow)*D_ + k0 + lcg + 4];
        float4 w0 = *(const float4*)&W[(size_t)(n0+lrow)*D_ + k0 + lcg];
        float4 w1 = *(const float4*)&W[(size_t)(n0+lrow)*D_ + k0 + lcg + 4];
        st4(&sA[lrow][lcg], a0); st4(&sA[lrow][lcg+4], a1);
        st4(&sW[lrow][lcg], w0); st4(&sW[lrow][lcg+4], w1);
        __syncthreads();
        #pragma unroll 8
        for (int kk = 0; kk < 32; ++kk) {
            float af[4], wf[4];
            #pragma unroll
            for (int a = 0; a < 4; ++a) af[a] = sA[tr*4+a][kk];
            #pragma unroll
            for (int c = 0; c < 4; ++c) wf[c] = sW[tc*4+c][kk];
            #pragma unroll
            for (int a = 0; a < 4; ++a)
                #pragma unroll
                for (int c = 0; c < 4; ++c)
                    acc[a][c] += af[a]*wf[c];
        }
        __syncthreads();
    }
    #pragma unroll
    for (int a = 0; a < 4; ++a)
        #pragma unroll
        for (int c = 0; c < 4; ++c)
            out[(size_t)(r0+tr*4+a)*H_ + n0+tc*4+c] = acc[a][c] + bias[n0+tc*4+c];
}

// ---------- scores[b,i,j,l] = sum_h relu(left[b,i,h]+right[b,j,h]+de[bkt,h])*out_w[l,h] + out_b[l]
// grid (K/64 j-tiles, K i, B), block 256. out tile 64j x 64l.
__global__ __launch_bounds__(256) void scores_kernel(
    const float* __restrict__ leftb, const float* __restrict__ rightb,
    const int* __restrict__ span_begin, const int* __restrict__ span_end,
    const float* __restrict__ dist_emb, const float* __restrict__ out_w,
    const float* __restrict__ out_b, float* __restrict__ S)
{
    const int j0 = blockIdx.x * 64;
    const int i = blockIdx.y;
    const int b = blockIdx.z;
    const int tid = threadIdx.x;
    const int lrow = tid >> 2, lcg = (tid & 3) * 16;
    const int tr = tid >> 4, tc = tid & 15;
    __shared__ float sLeft[H_];
    __shared__ int sBkt[64];
    __shared__ float sH[64][65];
    __shared__ float sW[64][65];
    sLeft[tid] = leftb[(size_t)(b*K_ + i)*H_ + tid];
    if (tid < 64) {
        int d = span_begin[b*K_ + j0 + tid] - span_end[b*K_ + i];
        if (d < 0) d = -d;
        sBkt[tid] = d > 63 ? 63 : d;
    }
    __syncthreads();
    float acc[4][4] = {};
    for (int hc = 0; hc < H_; hc += 64) {
        const float* wrow = &out_w[(size_t)lrow*H_ + hc + lcg];
        const float* rrow = &rightb[(size_t)(b*K_ + j0 + lrow)*H_ + hc + lcg];
        const float* drow = &dist_emb[(size_t)sBkt[lrow]*H_ + hc + lcg];
        #pragma unroll
        for (int u = 0; u < 4; ++u) {
            float4 w4 = *(const float4*)&wrow[u*4];
            st4(&sW[lrow][lcg + u*4], w4);
            float4 r4 = *(const float4*)&rrow[u*4];
            float4 d4 = *(const float4*)&drow[u*4];
            float4 h;
            h.x = fmaxf(0.f, sLeft[hc+lcg+u*4+0] + r4.x + d4.x);
            h.y = fmaxf(0.f, sLeft[hc+lcg+u*4+1] + r4.y + d4.y);
            h.z = fmaxf(0.f, sLeft[hc+lcg+u*4+2] + r4.z + d4.z);
            h.w = fmaxf(0.f, sLeft[hc+lcg+u*4+3] + r4.w + d4.w);
            st4(&sH[lrow][lcg + u*4], h);
        }
        __syncthreads();
        #pragma unroll 8
        for (int kk = 0; kk < 64; ++kk) {
            float hf[4], wf[4];
            #pragma unroll
            for (int a = 0; a < 4; ++a) hf[a] = sH[tr*4+a][kk];
            #pragma unroll
            for (int c = 0; c < 4; ++c) wf[c] = sW[tc*4+c][kk];
            #pragma unroll
            for (int a = 0; a < 4; ++a)
                #pragma unroll
                for (int c = 0; c < 4; ++c)
                    acc[a][c] += hf[a]*wf[c];
        }
        __syncthreads();
    }
    float4 ob = *(const float4*)&out_b[tc*4];
    #pragma unroll
    for (int a = 0; a < 4; ++a) {
        float4 v;
        v.x = acc[a][0] + ob.x; v.y = acc[a][1] + ob.y;
        v.z = acc[a][2] + ob.z; v.w = acc[a][3] + ob.w;
        *(float4*)&S[((size_t)(b*K_ + i)*K_ + j0 + tr*4 + a)*L_ + tc*4] = v;
    }
}

// ---------- ctxt1+ctxt2 fused GEMM with on-the-fly operands ----------
// c[b,m,d] += inv_len * sum_{t,l} sigmoid(S[...])·mask · W[d,l] · U[b,t,d]
// mode 0 (ctxt1): m=j, t=i, W=A_w.  mode 1 (ctxt2): m=i, t=j, W=B_w.
// grid (D/64, K/64, B*2modes*4splitK), block 256, atomicAdd into cacc.
__global__ __launch_bounds__(256) void ctxt_kernel(
    const float* __restrict__ S, const float* __restrict__ U,
    const float* __restrict__ A_w, const float* __restrict__ B_w,
    const float* __restrict__ mask, const float* __restrict__ lens,
    float* __restrict__ cacc)
{
    const int d0 = blockIdx.x * 64;
    const int m0 = blockIdx.y * 64;
    const int z = blockIdx.z;
    const int b = z >> 3;
    const int mode = (z >> 2) & 1;
    const int t0 = (z & 3) * 64;
    const int tid = threadIdx.x;
    const int lrow = tid >> 2, lcg = (tid & 3) * 16;
    const int tr = tid >> 4, tc = tid & 15;
    const float* __restrict__ W = mode ? B_w : A_w;
    const size_t sM = mode ? (size_t)(K_*L_) : (size_t)L_;
    const size_t sK = mode ? (size_t)L_ : (size_t)(K_*L_);
    const int mM = mode ? K_ : 1;
    const int mK = mode ? 1 : K_;
    const float* __restrict__ Sb = S + (size_t)b*K_*K_*L_;
    const float* __restrict__ Mb = mask + (size_t)b*K_*K_;
    __shared__ float sWt[L_][68];   // [l][dd]
    __shared__ float sU[64][68];    // [tt][dd]
    __shared__ float sP[64][65];    // [mm][l]
    #pragma unroll
    for (int u = 0; u < 4; ++u) {
        float4 w4 = *(const float4*)&W[(size_t)(d0+lrow)*L_ + lcg + u*4];
        sWt[lcg+u*4+0][lrow] = w4.x;
        sWt[lcg+u*4+1][lrow] = w4.y;
        sWt[lcg+u*4+2][lrow] = w4.z;
        sWt[lcg+u*4+3][lrow] = w4.w;
        float4 u4 = *(const float4*)&U[((size_t)b*K_ + t0 + lrow)*D_ + d0 + lcg + u*4];
        st4(&sU[lrow][lcg + u*4], u4);
    }
    const float inv_len = 1.0f / lens[b];
    float acc[4][4] = {};
    for (int tt = 0; tt < 64; ++tt) {
        __syncthreads();   // also covers initial sWt/sU staging on first iter
        {
            const float* srow = &Sb[(size_t)(m0+lrow)*sM + (size_t)(t0+tt)*sK + lcg];
            const float msk = Mb[(size_t)(m0+lrow)*mM + (size_t)(t0+tt)*mK];
            #pragma unroll
            for (int u = 0; u < 4; ++u) {
                float4 s4 = *(const float4*)&srow[u*4];
                float4 p;
                p.x = sigm(s4.x) * msk; p.y = sigm(s4.y) * msk;
                p.z = sigm(s4.z) * msk; p.w = sigm(s4.w) * msk;
                st4(&sP[lrow][lcg + u*4], p);
            }
        }
        __syncthreads();
        float sac[4][4] = {};
        #pragma unroll 8
        for (int l = 0; l < L_; ++l) {
            float pf[4];
            #pragma unroll
            for (int a = 0; a < 4; ++a) pf[a] = sP[tr*4+a][l];
            float4 w4 = *(const float4*)&sWt[l][tc*4];
            #pragma unroll
            for (int a = 0; a < 4; ++a) {
                sac[a][0] += pf[a]*w4.x;
                sac[a][1] += pf[a]*w4.y;
                sac[a][2] += pf[a]*w4.z;
                sac[a][3] += pf[a]*w4.w;
            }
        }
        float4 u4 = *(const float4*)&sU[tt][tc*4];
        #pragma unroll
        for (int a = 0; a < 4; ++a) {
            acc[a][0] += sac[a][0]*u4.x;
            acc[a][1] += sac[a][1]*u4.y;
            acc[a][2] += sac[a][2]*u4.z;
            acc[a][3] += sac[a][3]*u4.w;
        }
    }
    #pragma unroll
    for (int a = 0; a < 4; ++a)
        #pragma unroll
        for (int c = 0; c < 4; ++c)
            atomicAdd(&cacc[(size_t)(b*K_ + m0 + tr*4 + a)*D_ + d0 + tc*4 + c],
                      acc[a][c] * inv_len);
}

// ---------- gate: g = sigmoid([U,C]·gw^T + gb); Unext = g*U + (1-g)*C ----------
// grid (BK/64, D/64), block 256.
__global__ __launch_bounds__(256) void gate_kernel(
    const float* __restrict__ Ucur, const float* __restrict__ Cc,
    const float* __restrict__ gw, const float* __restrict__ gb,
    float* __restrict__ Unext)
{
    const int r0 = blockIdx.x * 64, n0 = blockIdx.y * 64;
    const int tid = threadIdx.x;
    const int lrow = tid >> 2, lcg = (tid & 3) * 8;
    const int tr = tid >> 4, tc = tid & 15;
    __shared__ float sA[64][33];
    __shared__ float sW[64][33];
    float acc[4][4] = {};
    for (int k0 = 0; k0 < 2*D_; k0 += 32) {
        const float* asrc = (k0 < D_) ? &Ucur[(size_t)(r0+lrow)*D_ + k0 + lcg]
                                      : &Cc[(size_t)(r0+lrow)*D_ + (k0 - D_) + lcg];
        float4 a0 = *(const float4*)&asrc[0];
        float4 a1 = *(const float4*)&asrc[4];
        float4 w0 = *(const float4*)&gw[(size_t)(n0+lrow)*(2*D_) + k0 + lcg];
        float4 w1 = *(const float4*)&gw[(size_t)(n0+lrow)*(2*D_) + k0 + lcg + 4];
        st4(&sA[lrow][lcg], a0); st4(&sA[lrow][lcg+4], a1);
        st4(&sW[lrow][lcg], w0); st4(&sW[lrow][lcg+4], w1);
        __syncthreads();
        #pragma unroll 8
        for (int kk = 0; kk < 32; ++kk) {
            float af[4], wf[4];
            #pragma unroll
            for (int a = 0; a < 4; ++a) af[a] = sA[tr*4+a][kk];
            #pragma unroll
            for (int c = 0; c < 4; ++c) wf[c] = sW[tc*4+c][kk];
            #pragma unroll
            for (int a = 0; a < 4; ++a)
                #pragma unroll
                for (int c = 0; c < 4; ++c)
                    acc[a][c] += af[a]*wf[c];
        }
        __syncthreads();
    }
    const int r = r0 + tr*4, n = n0 + tc*4;
    float4 gbv = *(const float4*)&gb[n];
    #pragma unroll
    for (int a = 0; a < 4; ++a) {
        float4 uv = *(const float4*)&Ucur[(size_t)(r+a)*D_ + n];
        float4 cv = *(const float4*)&Cc[(size_t)(r+a)*D_ + n];
        float4 o; float g;
        g = sigm(acc[a][0] + gbv.x); o.x = g*uv.x + (1.f-g)*cv.x;
        g = sigm(acc[a][1] + gbv.y); o.y = g*uv.y + (1.f-g)*cv.y;
        g = sigm(acc[a][2] + gbv.z); o.z = g*uv.z + (1.f-g)*cv.z;
        g = sigm(acc[a][3] + gbv.w); o.w = g*uv.w + (1.f-g)*cv.w;
        *(float4*)&Unext[(size_t)(r+a)*D_ + n] = o;
    }
}

// ---------- scatter updated rows into new_all ----------
__global__ __launch_bounds__(256) void scatter_kernel(
    const float* __restrict__ upd, const int* __restrict__ prune,
    const float* __restrict__ lens, float* __restrict__ out_all)
{
    const int blk = blockIdx.x;
    const int b = blk / K_, k = blk % K_;
    if ((float)k < lens[b]) {
        const int pi = prune[b*K_ + k];
        const int tid = threadIdx.x;
        if (tid < D_/4) {
            float4 v = *(const float4*)&upd[((size_t)b*K_ + k)*D_ + tid*4];
            *(float4*)&out_all[((size_t)b*N_ + pi)*D_ + tid*4] = v;
        }
    }
}

extern "C" void kernel_launch(void* const* d_in, const int* in_sizes, int n_in,
                              void* d_out, int out_size, void* d_ws, size_t ws_size,
                              hipStream_t stream) {
    (void)in_sizes; (void)n_in; (void)out_size; (void)ws_size;
    const float* all_span_vecs = (const float*)d_in[0];
    const float* span_vecs     = (const float*)d_in[1];
    const int*   span_begin    = (const int*)d_in[2];
    const int*   span_end      = (const int*)d_in[3];
    const float* mask          = (const float*)d_in[4];
    const float* lens          = (const float*)d_in[5];
    const int*   prune         = (const int*)d_in[6];
    const float* lw  = (const float*)d_in[7];
    const float* lb  = (const float*)d_in[8];
    const float* rw  = (const float*)d_in[9];
    const float* rb  = (const float*)d_in[10];
    const float* dist_emb = (const float*)d_in[11];
    const float* out_w    = (const float*)d_in[12];
    const float* out_b    = (const float*)d_in[13];
    const float* A_w = (const float*)d_in[14];
    const float* B_w = (const float*)d_in[15];
    const float* gw  = (const float*)d_in[16];
    const float* gb  = (const float*)d_in[17];

    float* out_all = (float*)d_out;
    float* out_upd = out_all + (size_t)B_*N_*D_;
    float* out_sc  = out_upd + (size_t)BK_*D_;

    float* ws     = (float*)d_ws;
    float* leftb  = ws;                       // BK*H
    float* rightb = leftb + (size_t)BK_*H_;   // BK*H
    float* U0     = rightb + (size_t)BK_*H_;  // BK*D
    float* U1     = U0 + (size_t)BK_*D_;      // BK*D
    float* cbuf   = U1 + (size_t)BK_*D_;      // BK*D

    hipMemcpyAsync(out_all, all_span_vecs, sizeof(float)*(size_t)B_*N_*D_,
                   hipMemcpyDeviceToDevice, stream);

    dim3 blk(256);
    lr_kernel<<<dim3(BK_/64, H_/64, 2), blk, 0, stream>>>(span_vecs, lw, lb, rw, rb, leftb, rightb);
    scores_kernel<<<dim3(K_/64, K_, B_), blk, 0, stream>>>(leftb, rightb, span_begin, span_end,
                                                           dist_emb, out_w, out_b, out_sc);
    const float* Ucur = span_vecs;
    float* nexts[3] = {U0, U1, out_upd};
    for (int it = 0; it < 3; ++it) {
        hipMemsetAsync(cbuf, 0, sizeof(float)*(size_t)BK_*D_, stream);
        ctxt_kernel<<<dim3(D_/64, K_/64, 16), blk, 0, stream>>>(out_sc, Ucur, A_w, B_w, mask, lens, cbuf);
        gate_kernel<<<dim3(BK_/64, D_/64), blk, 0, stream>>>(Ucur, cbuf, gw, gb, nexts[it]);
        Ucur = nexts[it];
        lr_kernel<<<dim3(BK_/64, H_/64, 2), blk, 0, stream>>>(Ucur, lw, lb, rw, rb, leftb, rightb);
        scores_kernel<<<dim3(K_/64, K_, B_), blk, 0, stream>>>(leftb, rightb, span_begin, span_end,
                                                               dist_emb, out_w, out_b, out_sc);
    }
    scatter_kernel<<<dim3(BK_), blk, 0, stream>>>(out_upd, prune, lens, out_all);
}

// Round 2
// 1163.485 us; speedup vs baseline: 1.9198x; 1.9198x over previous
//
#include <hip/hip_runtime.h>

#define B_ 2
#define N_ 2048
#define K_ 256
#define D_ 768
#define H_ 256
#define L_ 64
#define BK_ (B_*K_)

typedef __attribute__((ext_vector_type(8))) __bf16 bf16x8;
typedef __attribute__((ext_vector_type(8))) unsigned short ushort8;
typedef __attribute__((ext_vector_type(4))) unsigned short ushort4v;
typedef __attribute__((ext_vector_type(4))) float f32x4;

__device__ __forceinline__ float sigm(float x) { return 1.0f / (1.0f + __expf(-x)); }
__device__ __forceinline__ void st4(float* p, float4 v) { p[0]=v.x; p[1]=v.y; p[2]=v.z; p[3]=v.w; }

// round-to-nearest-even fp32 -> bf16
__device__ __forceinline__ unsigned short f2b(float f) {
    union { float f; unsigned int u; } v; v.f = f;
    unsigned int u = v.u;
    return (unsigned short)((u + 0x7FFFu + ((u >> 16) & 1u)) >> 16);
}
__device__ __forceinline__ bf16x8 ldb(const unsigned short* p) {
    ushort8 v = *(const ushort8*)p;
    return __builtin_bit_cast(bf16x8, v);
}

// ---------- convert A_w/B_w to bf16 (once per launch) ----------
__global__ __launch_bounds__(256) void wconv_kernel(
    const float* __restrict__ A_w, const float* __restrict__ B_w,
    unsigned short* __restrict__ WAb, unsigned short* __restrict__ WBb)
{
    int i = blockIdx.x * 256 + threadIdx.x;
    if (i < D_*L_) { WAb[i] = f2b(A_w[i]); WBb[i] = f2b(B_w[i]); }
}

// ---------- left/right projections: out[r,n] = U[r,:]·W[n,:] + bias[n] ----------
__global__ __launch_bounds__(256) void lr_kernel(
    const float* __restrict__ U,
    const float* __restrict__ lw, const float* __restrict__ lb,
    const float* __restrict__ rw, const float* __restrict__ rb,
    float* __restrict__ outL, float* __restrict__ outR)
{
    const int side = blockIdx.z;
    const float* __restrict__ W = side ? rw : lw;
    const float* __restrict__ bias = side ? rb : lb;
    float* __restrict__ out = side ? outR : outL;
    const int r0 = blockIdx.x * 64, n0 = blockIdx.y * 64;
    const int tid = threadIdx.x;
    const int lrow = tid >> 2, lcg = (tid & 3) * 8;
    const int tr = tid >> 4, tc = tid & 15;
    __shared__ float sA[64][33];
    __shared__ float sW[64][33];
    float acc[4][4] = {};
    for (int k0 = 0; k0 < D_; k0 += 32) {
        float4 a0 = *(const float4*)&U[(size_t)(r0+lrow)*D_ + k0 + lcg];
        float4 a1 = *(const float4*)&U[(size_t)(r0+lrow)*D_ + k0 + lcg + 4];
        float4 w0 = *(const float4*)&W[(size_t)(n0+lrow)*D_ + k0 + lcg];
        float4 w1 = *(const float4*)&W[(size_t)(n0+lrow)*D_ + k0 + lcg + 4];
        st4(&sA[lrow][lcg], a0); st4(&sA[lrow][lcg+4], a1);
        st4(&sW[lrow][lcg], w0); st4(&sW[lrow][lcg+4], w1);
        __syncthreads();
        #pragma unroll 8
        for (int kk = 0; kk < 32; ++kk) {
            float af[4], wf[4];
            #pragma unroll
            for (int a = 0; a < 4; ++a) af[a] = sA[tr*4+a][kk];
            #pragma unroll
            for (int c = 0; c < 4; ++c) wf[c] = sW[tc*4+c][kk];
            #pragma unroll
            for (int a = 0; a < 4; ++a)
                #pragma unroll
                for (int c = 0; c < 4; ++c)
                    acc[a][c] += af[a]*wf[c];
        }
        __syncthreads();
    }
    #pragma unroll
    for (int a = 0; a < 4; ++a)
        #pragma unroll
        for (int c = 0; c < 4; ++c)
            out[(size_t)(r0+tr*4+a)*H_ + n0+tc*4+c] = acc[a][c] + bias[n0+tc*4+c];
}

// ---------- scores + P emission ----------
// S[b,i,j,l] = sum_h relu(left+right+dist)*out_w[l,h] + out_b[l]
// P[b,i,j,l] = bf16(sigmoid(S)*mask), also transposed copy P^T[b,j,i,l].
__global__ __launch_bounds__(256) void scores_kernel(
    const float* __restrict__ leftb, const float* __restrict__ rightb,
    const int* __restrict__ span_begin, const int* __restrict__ span_end,
    const float* __restrict__ dist_emb, const float* __restrict__ out_w,
    const float* __restrict__ out_b, float* __restrict__ S,
    const float* __restrict__ mask,
    unsigned short* __restrict__ Pij, unsigned short* __restrict__ Pji,
    int writeP)
{
    const int j0 = blockIdx.x * 64;
    const int i = blockIdx.y;
    const int b = blockIdx.z;
    const int tid = threadIdx.x;
    const int lrow = tid >> 2, lcg = (tid & 3) * 16;
    const int tr = tid >> 4, tc = tid & 15;
    __shared__ float sLeft[H_];
    __shared__ int sBkt[64];
    __shared__ float sH[64][65];
    __shared__ float sW[64][65];
    sLeft[tid] = leftb[(size_t)(b*K_ + i)*H_ + tid];
    if (tid < 64) {
        int d = span_begin[b*K_ + j0 + tid] - span_end[b*K_ + i];
        if (d < 0) d = -d;
        sBkt[tid] = d > 63 ? 63 : d;
    }
    __syncthreads();
    float acc[4][4] = {};
    for (int hc = 0; hc < H_; hc += 64) {
        const float* wrow = &out_w[(size_t)lrow*H_ + hc + lcg];
        const float* rrow = &rightb[(size_t)(b*K_ + j0 + lrow)*H_ + hc + lcg];
        const float* drow = &dist_emb[(size_t)sBkt[lrow]*H_ + hc + lcg];
        #pragma unroll
        for (int u = 0; u < 4; ++u) {
            float4 w4 = *(const float4*)&wrow[u*4];
            st4(&sW[lrow][lcg + u*4], w4);
            float4 r4 = *(const float4*)&rrow[u*4];
            float4 d4 = *(const float4*)&drow[u*4];
            float4 h;
            h.x = fmaxf(0.f, sLeft[hc+lcg+u*4+0] + r4.x + d4.x);
            h.y = fmaxf(0.f, sLeft[hc+lcg+u*4+1] + r4.y + d4.y);
            h.z = fmaxf(0.f, sLeft[hc+lcg+u*4+2] + r4.z + d4.z);
            h.w = fmaxf(0.f, sLeft[hc+lcg+u*4+3] + r4.w + d4.w);
            st4(&sH[lrow][lcg + u*4], h);
        }
        __syncthreads();
        #pragma unroll 8
        for (int kk = 0; kk < 64; ++kk) {
            float hf[4], wf[4];
            #pragma unroll
            for (int a = 0; a < 4; ++a) hf[a] = sH[tr*4+a][kk];
            #pragma unroll
            for (int c = 0; c < 4; ++c) wf[c] = sW[tc*4+c][kk];
            #pragma unroll
            for (int a = 0; a < 4; ++a)
                #pragma unroll
                for (int c = 0; c < 4; ++c)
                    acc[a][c] += hf[a]*wf[c];
        }
        __syncthreads();
    }
    float4 ob = *(const float4*)&out_b[tc*4];
    #pragma unroll
    for (int a = 0; a < 4; ++a) {
        const int j = j0 + tr*4 + a;
        float4 v;
        v.x = acc[a][0] + ob.x; v.y = acc[a][1] + ob.y;
        v.z = acc[a][2] + ob.z; v.w = acc[a][3] + ob.w;
        *(float4*)&S[((size_t)(b*K_ + i)*K_ + j)*L_ + tc*4] = v;
        if (writeP) {
            const float msk = mask[(size_t)(b*K_ + i)*K_ + j];
            ushort4v p;
            p.x = f2b(sigm(v.x) * msk);
            p.y = f2b(sigm(v.y) * msk);
            p.z = f2b(sigm(v.z) * msk);
            p.w = f2b(sigm(v.w) * msk);
            *(ushort4v*)&Pij[((size_t)(b*K_ + i)*K_ + j)*L_ + tc*4] = p;
            *(ushort4v*)&Pji[((size_t)(b*K_ + j)*K_ + i)*L_ + tc*4] = p;
        }
    }
}

// ---------- ctxt via bf16 MFMA ----------
// C[b,m,d] += inv_len * sum_t u[t,d] * sum_l P[t,m,l]*W[d,l]
// mode 0: P=Pij (t=i,m=j), W=A_w.  mode 1: P=Pji (t=j,m=i), W=B_w.
// 1-D grid 768: g=bid%64 is the P-tile group (z*4+mt) so the 12 d-tiles of a
// group hit the same XCD (round-robin %8) for L2 locality of the P stream.
__global__ __launch_bounds__(256) void ctxt_kernel(
    const unsigned short* __restrict__ Pij, const unsigned short* __restrict__ Pji,
    const float* __restrict__ U,
    const unsigned short* __restrict__ WAb, const unsigned short* __restrict__ WBb,
    const float* __restrict__ lens, float* __restrict__ cacc)
{
    const int tid = threadIdx.x;
    const int bid = blockIdx.x;
    const int g = bid & 63;
    const int d0 = (bid >> 6) << 6;
    const int m0 = (g & 3) << 6;
    const int z = g >> 2;
    const int b = z >> 3;
    const int mode = (z >> 2) & 1;
    const int t0 = (z & 3) << 6;
    const unsigned short* __restrict__ Pm = mode ? Pji : Pij;
    const unsigned short* __restrict__ Wb = mode ? WBb : WAb;

    const int lane = tid & 63, w = tid >> 6;
    const int col = lane & 15, quad = lane >> 4;

    __shared__ unsigned short sP[64][72]; // 144B row stride: uniform bank spread
    __shared__ float sU[64][68];          // padded: conflict-free staging

    // stage U tile [t][d0..d0+64)
    {
        const int row = tid >> 2, cg = (tid & 3) * 16;
        const float* usrc = &U[((size_t)(b*K_ + t0 + row))*D_ + d0 + cg];
        #pragma unroll
        for (int u = 0; u < 4; ++u) {
            float4 v = *(const float4*)&usrc[u*4];
            *(float4*)&sU[row][cg + u*4] = v;
        }
    }
    // B fragments: B[k=l][n=d] row-major source = W[d][l] rows, contiguous 16B
    bf16x8 bw[4][2];
    #pragma unroll
    for (int dt = 0; dt < 4; ++dt)
        #pragma unroll
        for (int kc = 0; kc < 2; ++kc)
            bw[dt][kc] = ldb(&Wb[(size_t)(d0 + dt*16 + col)*L_ + kc*32 + quad*8]);

    f32x4 acc[4] = {};
    const int lrow = tid >> 2, c16 = (tid & 3) * 16;
    const unsigned short* psrc0 = &Pm[((size_t)(b*K_ + t0)*K_ + m0 + lrow)*L_ + c16];
    const int arow = w*16 + col;

    for (int t = 0; t < 64; ++t) {
        __syncthreads();
        {
            const unsigned short* src = psrc0 + (size_t)t * (K_*L_);
            ushort8 v0 = *(const ushort8*)&src[0];
            ushort8 v1 = *(const ushort8*)&src[8];
            *(ushort8*)&sP[lrow][c16] = v0;
            *(ushort8*)&sP[lrow][c16 + 8] = v1;
        }
        __syncthreads();
        bf16x8 a0 = ldb(&sP[arow][quad*8]);
        bf16x8 a1 = ldb(&sP[arow][32 + quad*8]);
        #pragma unroll
        for (int dt = 0; dt < 4; ++dt) {
            f32x4 gacc = {0.f, 0.f, 0.f, 0.f};
            gacc = __builtin_amdgcn_mfma_f32_16x16x32_bf16(a0, bw[dt][0], gacc, 0, 0, 0);
            gacc = __builtin_amdgcn_mfma_f32_16x16x32_bf16(a1, bw[dt][1], gacc, 0, 0, 0);
            const float uu = sU[t][dt*16 + col];
            acc[dt] += gacc * uu;
        }
    }
    const float inv_len = 1.0f / lens[b];
    #pragma unroll
    for (int dt = 0; dt < 4; ++dt)
        #pragma unroll
        for (int r = 0; r < 4; ++r) {
            const int m = m0 + w*16 + quad*4 + r;  // C/D: row=(lane>>4)*4+reg, col=lane&15
            atomicAdd(&cacc[((size_t)(b*K_) + m)*D_ + d0 + dt*16 + col],
                      acc[dt][r] * inv_len);
        }
}

// ---------- gate: g = sigmoid([U,C]·gw^T + gb); Unext = g*U + (1-g)*C ----------
__global__ __launch_bounds__(256) void gate_kernel(
    const float* __restrict__ Ucur, const float* __restrict__ Cc,
    const float* __restrict__ gw, const float* __restrict__ gb,
    float* __restrict__ Unext)
{
    const int r0 = blockIdx.x * 64, n0 = blockIdx.y * 64;
    const int tid = threadIdx.x;
    const int lrow = tid >> 2, lcg = (tid & 3) * 8;
    const int tr = tid >> 4, tc = tid & 15;
    __shared__ float sA[64][33];
    __shared__ float sW[64][33];
    float acc[4][4] = {};
    for (int k0 = 0; k0 < 2*D_; k0 += 32) {
        const float* asrc = (k0 < D_) ? &Ucur[(size_t)(r0+lrow)*D_ + k0 + lcg]
                                      : &Cc[(size_t)(r0+lrow)*D_ + (k0 - D_) + lcg];
        float4 a0 = *(const float4*)&asrc[0];
        float4 a1 = *(const float4*)&asrc[4];
        float4 w0 = *(const float4*)&gw[(size_t)(n0+lrow)*(2*D_) + k0 + lcg];
        float4 w1 = *(const float4*)&gw[(size_t)(n0+lrow)*(2*D_) + k0 + lcg + 4];
        st4(&sA[lrow][lcg], a0); st4(&sA[lrow][lcg+4], a1);
        st4(&sW[lrow][lcg], w0); st4(&sW[lrow][lcg+4], w1);
        __syncthreads();
        #pragma unroll 8
        for (int kk = 0; kk < 32; ++kk) {
            float af[4], wf[4];
            #pragma unroll
            for (int a = 0; a < 4; ++a) af[a] = sA[tr*4+a][kk];
            #pragma unroll
            for (int c = 0; c < 4; ++c) wf[c] = sW[tc*4+c][kk];
            #pragma unroll
            for (int a = 0; a < 4; ++a)
                #pragma unroll
                for (int c = 0; c < 4; ++c)
                    acc[a][c] += af[a]*wf[c];
        }
        __syncthreads();
    }
    const int r = r0 + tr*4, n = n0 + tc*4;
    float4 gbv = *(const float4*)&gb[n];
    #pragma unroll
    for (int a = 0; a < 4; ++a) {
        float4 uv = *(const float4*)&Ucur[(size_t)(r+a)*D_ + n];
        float4 cv = *(const float4*)&Cc[(size_t)(r+a)*D_ + n];
        float4 o; float g;
        g = sigm(acc[a][0] + gbv.x); o.x = g*uv.x + (1.f-g)*cv.x;
        g = sigm(acc[a][1] + gbv.y); o.y = g*uv.y + (1.f-g)*cv.y;
        g = sigm(acc[a][2] + gbv.z); o.z = g*uv.z + (1.f-g)*cv.z;
        g = sigm(acc[a][3] + gbv.w); o.w = g*uv.w + (1.f-g)*cv.w;
        *(float4*)&Unext[(size_t)(r+a)*D_ + n] = o;
    }
}

// ---------- scatter updated rows into new_all ----------
__global__ __launch_bounds__(256) void scatter_kernel(
    const float* __restrict__ upd, const int* __restrict__ prune,
    const float* __restrict__ lens, float* __restrict__ out_all)
{
    const int blk = blockIdx.x;
    const int b = blk / K_, k = blk % K_;
    if ((float)k < lens[b]) {
        const int pi = prune[b*K_ + k];
        const int tid = threadIdx.x;
        if (tid < D_/4) {
            float4 v = *(const float4*)&upd[((size_t)b*K_ + k)*D_ + tid*4];
            *(float4*)&out_all[((size_t)b*N_ + pi)*D_ + tid*4] = v;
        }
    }
}

extern "C" void kernel_launch(void* const* d_in, const int* in_sizes, int n_in,
                              void* d_out, int out_size, void* d_ws, size_t ws_size,
                              hipStream_t stream) {
    (void)in_sizes; (void)n_in; (void)out_size; (void)ws_size;
    const float* all_span_vecs = (const float*)d_in[0];
    const float* span_vecs     = (const float*)d_in[1];
    const int*   span_begin    = (const int*)d_in[2];
    const int*   span_end      = (const int*)d_in[3];
    const float* mask          = (const float*)d_in[4];
    const float* lens          = (const float*)d_in[5];
    const int*   prune         = (const int*)d_in[6];
    const float* lw  = (const float*)d_in[7];
    const float* lb  = (const float*)d_in[8];
    const float* rw  = (const float*)d_in[9];
    const float* rb  = (const float*)d_in[10];
    const float* dist_emb = (const float*)d_in[11];
    const float* out_w    = (const float*)d_in[12];
    const float* out_b    = (const float*)d_in[13];
    const float* A_w = (const float*)d_in[14];
    const float* B_w = (const float*)d_in[15];
    const float* gw  = (const float*)d_in[16];
    const float* gb  = (const float*)d_in[17];

    float* out_all = (float*)d_out;
    float* out_upd = out_all + (size_t)B_*N_*D_;
    float* out_sc  = out_upd + (size_t)BK_*D_;

    float* ws     = (float*)d_ws;
    float* leftb  = ws;                       // BK*H
    float* rightb = leftb + (size_t)BK_*H_;   // BK*H
    float* U0     = rightb + (size_t)BK_*H_;  // BK*D
    float* U1     = U0 + (size_t)BK_*D_;      // BK*D
    float* cbuf   = U1 + (size_t)BK_*D_;      // BK*D
    unsigned short* WAb = (unsigned short*)(cbuf + (size_t)BK_*D_); // D*L bf16
    unsigned short* WBb = WAb + (size_t)D_*L_;
    unsigned short* Pij = WBb + (size_t)D_*L_;                      // B*K*K*L bf16
    unsigned short* Pji = Pij + (size_t)B_*K_*K_*L_;

    hipMemcpyAsync(out_all, all_span_vecs, sizeof(float)*(size_t)B_*N_*D_,
                   hipMemcpyDeviceToDevice, stream);

    dim3 blk(256);
    wconv_kernel<<<dim3((D_*L_+255)/256), blk, 0, stream>>>(A_w, B_w, WAb, WBb);
    lr_kernel<<<dim3(BK_/64, H_/64, 2), blk, 0, stream>>>(span_vecs, lw, lb, rw, rb, leftb, rightb);
    scores_kernel<<<dim3(K_/64, K_, B_), blk, 0, stream>>>(leftb, rightb, span_begin, span_end,
                                                           dist_emb, out_w, out_b, out_sc,
                                                           mask, Pij, Pji, 1);
    const float* Ucur = span_vecs;
    float* nexts[3] = {U0, U1, out_upd};
    for (int it = 0; it < 3; ++it) {
        hipMemsetAsync(cbuf, 0, sizeof(float)*(size_t)BK_*D_, stream);
        ctxt_kernel<<<dim3(768), blk, 0, stream>>>(Pij, Pji, Ucur, WAb, WBb, lens, cbuf);
        gate_kernel<<<dim3(BK_/64, D_/64), blk, 0, stream>>>(Ucur, cbuf, gw, gb, nexts[it]);
        Ucur = nexts[it];
        lr_kernel<<<dim3(BK_/64, H_/64, 2), blk, 0, stream>>>(Ucur, lw, lb, rw, rb, leftb, rightb);
        scores_kernel<<<dim3(K_/64, K_, B_), blk, 0, stream>>>(leftb, rightb, span_begin, span_end,
                                                               dist_emb, out_w, out_b, out_sc,
                                                               mask, Pij, Pji, it == 2 ? 0 : 1);
    }
    scatter_kernel<<<dim3(BK_), blk, 0, stream>>>(out_upd, prune, lens, out_all);
}

// Round 3
// 668.902 us; speedup vs baseline: 3.3393x; 1.7394x over previous
//
#include <hip/hip_runtime.h>

#define B_ 2
#define N_ 2048
#define K_ 256
#define D_ 768
#define H_ 256
#define L_ 64
#define BK_ (B_*K_)

typedef __attribute__((ext_vector_type(8))) __bf16 bf16x8;
typedef __attribute__((ext_vector_type(8))) unsigned short ushort8;
typedef __attribute__((ext_vector_type(4))) unsigned short ushort4v;
typedef __attribute__((ext_vector_type(4))) float f32x4;

__device__ __forceinline__ float sigm(float x) { return 1.0f / (1.0f + __expf(-x)); }

// round-to-nearest-even fp32 -> bf16
__device__ __forceinline__ unsigned short f2b(float f) {
    union { float f; unsigned int u; } v; v.f = f;
    unsigned int u = v.u;
    return (unsigned short)((u + 0x7FFFu + ((u >> 16) & 1u)) >> 16);
}
__device__ __forceinline__ bf16x8 ldb(const unsigned short* p) {
    ushort8 v = *(const ushort8*)p;
    return __builtin_bit_cast(bf16x8, v);
}

// ---------- one-shot fp32->bf16 conversion of all static operands ----------
// segments: lw,rw (H*D each), out_w (L*H), gw (D*2D), A_w,B_w (D*L), span_vecs (BK*D)
__global__ __launch_bounds__(256) void conv_all(
    const float* __restrict__ lw, const float* __restrict__ rw,
    const float* __restrict__ ow, const float* __restrict__ gw,
    const float* __restrict__ aw, const float* __restrict__ bw,
    const float* __restrict__ sv,
    unsigned short* __restrict__ lwb, unsigned short* __restrict__ rwb,
    unsigned short* __restrict__ owb, unsigned short* __restrict__ gwb,
    unsigned short* __restrict__ wab, unsigned short* __restrict__ wbb,
    unsigned short* __restrict__ ub)
{
    int i4 = (blockIdx.x * 256 + threadIdx.x) * 4;
    const float* src; unsigned short* dst; int off;
    if      (i4 <  196608) { src = lw; dst = lwb; off = 0; }
    else if (i4 <  393216) { src = rw; dst = rwb; off = 196608; }
    else if (i4 <  409600) { src = ow; dst = owb; off = 393216; }
    else if (i4 < 1589248) { src = gw; dst = gwb; off = 409600; }
    else if (i4 < 1638400) { src = aw; dst = wab; off = 1589248; }
    else if (i4 < 1687552) { src = bw; dst = wbb; off = 1638400; }
    else if (i4 < 2080768) { src = sv; dst = ub;  off = 1687552; }
    else return;
    int j = i4 - off;
    float4 v = *(const float4*)&src[j];
    ushort4v p; p.x = f2b(v.x); p.y = f2b(v.y); p.z = f2b(v.z); p.w = f2b(v.w);
    *(ushort4v*)&dst[j] = p;
}

// ---------- fp32 -> bf16 for the ctxt accumulator ----------
__global__ __launch_bounds__(256) void cconv_kernel(
    const float* __restrict__ c, unsigned short* __restrict__ cb)
{
    int i4 = (blockIdx.x * 256 + threadIdx.x) * 4;
    if (i4 < BK_*D_) {
        float4 v = *(const float4*)&c[i4];
        ushort4v p; p.x = f2b(v.x); p.y = f2b(v.y); p.z = f2b(v.z); p.w = f2b(v.w);
        *(ushort4v*)&cb[i4] = p;
    }
}

// ---------- left/right projections via MFMA: out[r,n] = Ub[r,:]·Wb[n,:] + bias[n]
// grid (BK/64, H/64, 2), block 256 (4 waves, each 16 rows x 64 cols).
__global__ __launch_bounds__(256) void lr_mfma(
    const unsigned short* __restrict__ Ub,
    const unsigned short* __restrict__ lwb, const float* __restrict__ lb,
    const unsigned short* __restrict__ rwb, const float* __restrict__ rb,
    float* __restrict__ outL, float* __restrict__ outR)
{
    const int side = blockIdx.z;
    const unsigned short* __restrict__ W = side ? rwb : lwb;
    const float* __restrict__ bias = side ? rb : lb;
    float* __restrict__ out = side ? outR : outL;
    const int r0 = blockIdx.x * 64, n0 = blockIdx.y * 64;
    const int tid = threadIdx.x;
    const int w = tid >> 6, lane = tid & 63, col = lane & 15, quad = lane >> 4;
    const unsigned short* arow = &Ub[(size_t)(r0 + w*16 + col)*D_ + quad*8];
    f32x4 acc[4] = {};
    #pragma unroll 4
    for (int kc = 0; kc < D_; kc += 32) {
        bf16x8 a = ldb(arow + kc);
        #pragma unroll
        for (int nt = 0; nt < 4; ++nt) {
            bf16x8 bb = ldb(&W[(size_t)(n0 + nt*16 + col)*D_ + kc + quad*8]);
            acc[nt] = __builtin_amdgcn_mfma_f32_16x16x32_bf16(a, bb, acc[nt], 0, 0, 0);
        }
    }
    #pragma unroll
    for (int nt = 0; nt < 4; ++nt) {
        const int n = n0 + nt*16 + col;
        const float bv = bias[n];
        #pragma unroll
        for (int r = 0; r < 4; ++r)
            out[(size_t)(r0 + w*16 + quad*4 + r)*H_ + n] = acc[nt][r] + bv;
    }
}

// ---------- scores via MFMA ----------
// h[j,h] = relu(left[i,h] + right[j,h] + dist_emb[bkt(i,j),h]) -> bf16 LDS tile,
// then [64j x 64l] = h · out_w^T on MFMA.
// writeP: emit Pt[b][j][i][l] = bf16(sigmoid(S)*mask). else: emit S fp32 (final).
__global__ __launch_bounds__(256) void scores_mfma(
    const float* __restrict__ leftb, const float* __restrict__ rightb,
    const int* __restrict__ span_begin, const int* __restrict__ span_end,
    const float* __restrict__ dist_emb, const unsigned short* __restrict__ owb,
    const float* __restrict__ out_b, const float* __restrict__ mask,
    float* __restrict__ S, unsigned short* __restrict__ Pt, int writeP)
{
    const int j0 = blockIdx.x * 64;
    const int i  = blockIdx.y;
    const int b  = blockIdx.z;
    const int tid = threadIdx.x;
    __shared__ unsigned short sH[64][264];  // 528B row stride: (row+quad)%8 16B-chunk spread
    __shared__ float sLeft[H_];
    __shared__ float sMask[64];
    __shared__ int sBkt[64];
    sLeft[tid] = leftb[(size_t)(b*K_ + i)*H_ + tid];
    if (tid < 64) {
        int d = span_begin[b*K_ + j0 + tid] - span_end[b*K_ + i];
        if (d < 0) d = -d;
        sBkt[tid] = d > 63 ? 63 : d;
        sMask[tid] = mask[(size_t)(b*K_ + i)*K_ + j0 + tid];
    }
    __syncthreads();
    {
        const int row = tid >> 2, seg = tid & 3;
        const float* rrow = &rightb[(size_t)(b*K_ + j0 + row)*H_ + seg*64];
        const float* drow = &dist_emb[(size_t)sBkt[row]*H_ + seg*64];
        const float* lptr = &sLeft[seg*64];
        #pragma unroll
        for (int g = 0; g < 8; ++g) {
            float4 r0 = *(const float4*)&rrow[g*8];
            float4 r1 = *(const float4*)&rrow[g*8 + 4];
            float4 d0 = *(const float4*)&drow[g*8];
            float4 d1 = *(const float4*)&drow[g*8 + 4];
            ushort8 pk;
            pk[0] = f2b(fmaxf(0.f, lptr[g*8+0] + r0.x + d0.x));
            pk[1] = f2b(fmaxf(0.f, lptr[g*8+1] + r0.y + d0.y));
            pk[2] = f2b(fmaxf(0.f, lptr[g*8+2] + r0.z + d0.z));
            pk[3] = f2b(fmaxf(0.f, lptr[g*8+3] + r0.w + d0.w));
            pk[4] = f2b(fmaxf(0.f, lptr[g*8+4] + r1.x + d1.x));
            pk[5] = f2b(fmaxf(0.f, lptr[g*8+5] + r1.y + d1.y));
            pk[6] = f2b(fmaxf(0.f, lptr[g*8+6] + r1.z + d1.z));
            pk[7] = f2b(fmaxf(0.f, lptr[g*8+7] + r1.w + d1.w));
            *(ushort8*)&sH[row][seg*64 + g*8] = pk;
        }
    }
    __syncthreads();
    const int w = tid >> 6, lane = tid & 63, col = lane & 15, quad = lane >> 4;
    const int arow = w*16 + col;
    f32x4 acc[4] = {};
    #pragma unroll
    for (int kc = 0; kc < H_; kc += 32) {
        bf16x8 a = ldb(&sH[arow][kc + quad*8]);
        #pragma unroll
        for (int nt = 0; nt < 4; ++nt) {
            bf16x8 bb = ldb(&owb[(size_t)(nt*16 + col)*H_ + kc + quad*8]);
            acc[nt] = __builtin_amdgcn_mfma_f32_16x16x32_bf16(a, bb, acc[nt], 0, 0, 0);
        }
    }
    #pragma unroll
    for (int nt = 0; nt < 4; ++nt) {
        const int l = nt*16 + col;
        const float ob = out_b[l];
        #pragma unroll
        for (int r = 0; r < 4; ++r) {
            const int jj = w*16 + quad*4 + r;   // C/D: row=quad*4+reg
            const int j = j0 + jj;
            const float v = acc[nt][r] + ob;
            if (writeP) {
                Pt[(((size_t)b*K_ + j)*K_ + i)*L_ + l] = f2b(sigm(v) * sMask[jj]);
            } else {
                S[(((size_t)b*K_ + i)*K_ + j)*L_ + l] = v;
            }
        }
    }
}

// ---------- ctxt via bf16 MFMA ----------
// C[b,m,d] += inv_len * sum_t u[t,d] * sum_l P(t,m)[l]*W[d,l]
// P stored once as Pt[b][j][i][l] = p(i,j).
// mode 0 (ctxt1): t=i, m=j, W=A_w -> P(t,m)=Pt[m][t] (t-stride 64, row-stride K*64)
// mode 1 (ctxt2): t=j, m=i, W=B_w -> P(t,m)=Pt[t][m] (contiguous rows per t)
__global__ __launch_bounds__(256) void ctxt_kernel(
    const unsigned short* __restrict__ Pt, const float* __restrict__ U,
    const unsigned short* __restrict__ WAb, const unsigned short* __restrict__ WBb,
    const float* __restrict__ lens, float* __restrict__ cacc)
{
    const int tid = threadIdx.x;
    const int bid = blockIdx.x;
    const int g = bid & 63;
    const int d0 = (bid >> 6) << 6;
    const int m0 = (g & 3) << 6;
    const int z = g >> 2;
    const int b = z >> 3;
    const int mode = (z >> 2) & 1;
    const int t0 = (z & 3) << 6;
    const unsigned short* __restrict__ Wb = mode ? WBb : WAb;

    const int lane = tid & 63, w = tid >> 6;
    const int col = lane & 15, quad = lane >> 4;

    __shared__ unsigned short sP[64][72];
    __shared__ float sU[64][68];

    {
        const int row = tid >> 2, cg = (tid & 3) * 16;
        const float* usrc = &U[((size_t)(b*K_ + t0 + row))*D_ + d0 + cg];
        #pragma unroll
        for (int u = 0; u < 4; ++u) {
            float4 v = *(const float4*)&usrc[u*4];
            *(float4*)&sU[row][cg + u*4] = v;
        }
    }
    bf16x8 bw[4][2];
    #pragma unroll
    for (int dt = 0; dt < 4; ++dt)
        #pragma unroll
        for (int kc = 0; kc < 2; ++kc)
            bw[dt][kc] = ldb(&Wb[(size_t)(d0 + dt*16 + col)*L_ + kc*32 + quad*8]);

    f32x4 acc[4] = {};
    const int lrow = tid >> 2, c16 = (tid & 3) * 16;
    const unsigned short* psrc0;
    size_t tstep;
    if (mode) {
        psrc0 = &Pt[(((size_t)b*K_ + t0)*K_ + m0 + lrow)*L_ + c16];
        tstep = (size_t)K_ * L_;
    } else {
        psrc0 = &Pt[(((size_t)b*K_ + m0 + lrow)*K_ + t0)*L_ + c16];
        tstep = (size_t)L_;
    }
    const int arow = w*16 + col;

    for (int t = 0; t < 64; ++t) {
        __syncthreads();
        {
            const unsigned short* src = psrc0 + (size_t)t * tstep;
            ushort8 v0 = *(const ushort8*)&src[0];
            ushort8 v1 = *(const ushort8*)&src[8];
            *(ushort8*)&sP[lrow][c16] = v0;
            *(ushort8*)&sP[lrow][c16 + 8] = v1;
        }
        __syncthreads();
        bf16x8 a0 = ldb(&sP[arow][quad*8]);
        bf16x8 a1 = ldb(&sP[arow][32 + quad*8]);
        #pragma unroll
        for (int dt = 0; dt < 4; ++dt) {
            f32x4 gacc = {0.f, 0.f, 0.f, 0.f};
            gacc = __builtin_amdgcn_mfma_f32_16x16x32_bf16(a0, bw[dt][0], gacc, 0, 0, 0);
            gacc = __builtin_amdgcn_mfma_f32_16x16x32_bf16(a1, bw[dt][1], gacc, 0, 0, 0);
            const float uu = sU[t][dt*16 + col];
            acc[dt] += gacc * uu;
        }
    }
    const float inv_len = 1.0f / lens[b];
    #pragma unroll
    for (int dt = 0; dt < 4; ++dt)
        #pragma unroll
        for (int r = 0; r < 4; ++r) {
            const int m = m0 + w*16 + quad*4 + r;
            atomicAdd(&cacc[((size_t)(b*K_) + m)*D_ + d0 + dt*16 + col],
                      acc[dt][r] * inv_len);
        }
}

// ---------- gate via MFMA: logit = [Ub|Cb]·gw^T; Unext = g*U + (1-g)*C ----------
// grid (BK/64, D/64), block 256.
__global__ __launch_bounds__(256) void gate_mfma(
    const unsigned short* __restrict__ Ub, const unsigned short* __restrict__ Cb,
    const unsigned short* __restrict__ gwb, const float* __restrict__ gb,
    const float* __restrict__ Ucur, const float* __restrict__ Cc,
    float* __restrict__ Unext, unsigned short* __restrict__ Ubnext)
{
    const int r0 = blockIdx.x * 64, n0 = blockIdx.y * 64;
    const int tid = threadIdx.x;
    const int w = tid >> 6, lane = tid & 63, col = lane & 15, quad = lane >> 4;
    const unsigned short* arow_u = &Ub[(size_t)(r0 + w*16 + col)*D_ + quad*8];
    const unsigned short* arow_c = &Cb[(size_t)(r0 + w*16 + col)*D_ + quad*8];
    f32x4 acc[4] = {};
    #pragma unroll 4
    for (int kc = 0; kc < D_; kc += 32) {
        bf16x8 a = ldb(arow_u + kc);
        #pragma unroll
        for (int nt = 0; nt < 4; ++nt) {
            bf16x8 bb = ldb(&gwb[(size_t)(n0 + nt*16 + col)*(2*D_) + kc + quad*8]);
            acc[nt] = __builtin_amdgcn_mfma_f32_16x16x32_bf16(a, bb, acc[nt], 0, 0, 0);
        }
    }
    #pragma unroll 4
    for (int kc = 0; kc < D_; kc += 32) {
        bf16x8 a = ldb(arow_c + kc);
        #pragma unroll
        for (int nt = 0; nt < 4; ++nt) {
            bf16x8 bb = ldb(&gwb[(size_t)(n0 + nt*16 + col)*(2*D_) + D_ + kc + quad*8]);
            acc[nt] = __builtin_amdgcn_mfma_f32_16x16x32_bf16(a, bb, acc[nt], 0, 0, 0);
        }
    }
    #pragma unroll
    for (int nt = 0; nt < 4; ++nt) {
        const int n = n0 + nt*16 + col;
        const float gbv = gb[n];
        #pragma unroll
        for (int r = 0; r < 4; ++r) {
            const size_t idx = (size_t)(r0 + w*16 + quad*4 + r)*D_ + n;
            const float gg = sigm(acc[nt][r] + gbv);
            const float o = gg * Ucur[idx] + (1.f - gg) * Cc[idx];
            Unext[idx] = o;
            Ubnext[idx] = f2b(o);
        }
    }
}

// ---------- scatter updated rows into new_all ----------
__global__ __launch_bounds__(256) void scatter_kernel(
    const float* __restrict__ upd, const int* __restrict__ prune,
    const float* __restrict__ lens, float* __restrict__ out_all)
{
    const int blk = blockIdx.x;
    const int b = blk / K_, k = blk % K_;
    if ((float)k < lens[b]) {
        const int pi = prune[b*K_ + k];
        const int tid = threadIdx.x;
        if (tid < D_/4) {
            float4 v = *(const float4*)&upd[((size_t)b*K_ + k)*D_ + tid*4];
            *(float4*)&out_all[((size_t)b*N_ + pi)*D_ + tid*4] = v;
        }
    }
}

extern "C" void kernel_launch(void* const* d_in, const int* in_sizes, int n_in,
                              void* d_out, int out_size, void* d_ws, size_t ws_size,
                              hipStream_t stream) {
    (void)in_sizes; (void)n_in; (void)out_size; (void)ws_size;
    const float* all_span_vecs = (const float*)d_in[0];
    const float* span_vecs     = (const float*)d_in[1];
    const int*   span_begin    = (const int*)d_in[2];
    const int*   span_end      = (const int*)d_in[3];
    const float* mask          = (const float*)d_in[4];
    const float* lens          = (const float*)d_in[5];
    const int*   prune         = (const int*)d_in[6];
    const float* lw  = (const float*)d_in[7];
    const float* lb  = (const float*)d_in[8];
    const float* rw  = (const float*)d_in[9];
    const float* rb  = (const float*)d_in[10];
    const float* dist_emb = (const float*)d_in[11];
    const float* out_w    = (const float*)d_in[12];
    const float* out_b    = (const float*)d_in[13];
    const float* A_w = (const float*)d_in[14];
    const float* B_w = (const float*)d_in[15];
    const float* gw  = (const float*)d_in[16];
    const float* gb  = (const float*)d_in[17];

    float* out_all = (float*)d_out;
    float* out_upd = out_all + (size_t)B_*N_*D_;
    float* out_sc  = out_upd + (size_t)BK_*D_;

    float* ws     = (float*)d_ws;
    float* leftb  = ws;                       // BK*H
    float* rightb = leftb + (size_t)BK_*H_;   // BK*H
    float* U0     = rightb + (size_t)BK_*H_;  // BK*D
    float* U1     = U0 + (size_t)BK_*D_;      // BK*D
    float* cbuf   = U1 + (size_t)BK_*D_;      // BK*D
    unsigned short* WAb = (unsigned short*)(cbuf + (size_t)BK_*D_);
    unsigned short* WBb = WAb + (size_t)D_*L_;
    unsigned short* lwb = WBb + (size_t)D_*L_;
    unsigned short* rwb = lwb + (size_t)H_*D_;
    unsigned short* owb = rwb + (size_t)H_*D_;
    unsigned short* gwb = owb + (size_t)L_*H_;
    unsigned short* Ub0 = gwb + (size_t)D_*2*D_;
    unsigned short* Ub1 = Ub0 + (size_t)BK_*D_;
    unsigned short* Cb  = Ub1 + (size_t)BK_*D_;
    unsigned short* Pt  = Cb  + (size_t)BK_*D_;   // B*K*K*L bf16

    hipMemcpyAsync(out_all, all_span_vecs, sizeof(float)*(size_t)B_*N_*D_,
                   hipMemcpyDeviceToDevice, stream);

    dim3 blk(256);
    conv_all<<<dim3(2032), blk, 0, stream>>>(lw, rw, out_w, gw, A_w, B_w, span_vecs,
                                             lwb, rwb, owb, gwb, WAb, WBb, Ub0);
    lr_mfma<<<dim3(BK_/64, H_/64, 2), blk, 0, stream>>>(Ub0, lwb, lb, rwb, rb, leftb, rightb);
    scores_mfma<<<dim3(K_/64, K_, B_), blk, 0, stream>>>(leftb, rightb, span_begin, span_end,
                                                         dist_emb, owb, out_b, mask,
                                                         out_sc, Pt, 1);
    const float* Ucur = span_vecs;
    const unsigned short* Ubcur = Ub0;
    float* nexts[3] = {U0, U1, out_upd};
    unsigned short* nextsUb[3] = {Ub1, Ub0, Ub1};
    for (int it = 0; it < 3; ++it) {
        hipMemsetAsync(cbuf, 0, sizeof(float)*(size_t)BK_*D_, stream);
        ctxt_kernel<<<dim3(768), blk, 0, stream>>>(Pt, Ucur, WAb, WBb, lens, cbuf);
        cconv_kernel<<<dim3(BK_*D_/4/256), blk, 0, stream>>>(cbuf, Cb);
        gate_mfma<<<dim3(BK_/64, D_/64), blk, 0, stream>>>(Ubcur, Cb, gwb, gb,
                                                           Ucur, cbuf, nexts[it], nextsUb[it]);
        Ucur = nexts[it];
        Ubcur = nextsUb[it];
        lr_mfma<<<dim3(BK_/64, H_/64, 2), blk, 0, stream>>>(Ubcur, lwb, lb, rwb, rb, leftb, rightb);
        scores_mfma<<<dim3(K_/64, K_, B_), blk, 0, stream>>>(leftb, rightb, span_begin, span_end,
                                                             dist_emb, owb, out_b, mask,
                                                             out_sc, Pt, it == 2 ? 0 : 1);
    }
    scatter_kernel<<<dim3(BK_), blk, 0, stream>>>(out_upd, prune, lens, out_all);
}

// Round 4
// 572.257 us; speedup vs baseline: 3.9032x; 1.1689x over previous
//
#include <hip/hip_runtime.h>

#define B_ 2
#define N_ 2048
#define K_ 256
#define D_ 768
#define H_ 256
#define L_ 64
#define BK_ (B_*K_)

typedef __attribute__((ext_vector_type(8))) __bf16 bf16x8;
typedef __attribute__((ext_vector_type(8))) unsigned short ushort8;
typedef __attribute__((ext_vector_type(4))) unsigned short ushort4v;
typedef __attribute__((ext_vector_type(4))) float f32x4;

__device__ __forceinline__ float sigm(float x) { return 1.0f / (1.0f + __expf(-x)); }

// round-to-nearest-even fp32 -> bf16
__device__ __forceinline__ unsigned short f2b(float f) {
    union { float f; unsigned int u; } v; v.f = f;
    unsigned int u = v.u;
    return (unsigned short)((u + 0x7FFFu + ((u >> 16) & 1u)) >> 16);
}
__device__ __forceinline__ bf16x8 ldb(const unsigned short* p) {
    ushort8 v = *(const ushort8*)p;
    return __builtin_bit_cast(bf16x8, v);
}
// load 8 fp32 -> bf16x8
__device__ __forceinline__ bf16x8 cvt8(const float* p) {
    float4 v0 = *(const float4*)p;
    float4 v1 = *(const float4*)(p + 4);
    ushort8 u;
    u[0] = f2b(v0.x); u[1] = f2b(v0.y); u[2] = f2b(v0.z); u[3] = f2b(v0.w);
    u[4] = f2b(v1.x); u[5] = f2b(v1.y); u[6] = f2b(v1.z); u[7] = f2b(v1.w);
    return __builtin_bit_cast(bf16x8, u);
}

// ---------- one-shot fp32->bf16 conversion of all static operands ----------
__global__ __launch_bounds__(256) void conv_all(
    const float* __restrict__ lw, const float* __restrict__ rw,
    const float* __restrict__ ow, const float* __restrict__ gw,
    const float* __restrict__ aw, const float* __restrict__ bw,
    const float* __restrict__ sv,
    unsigned short* __restrict__ lwb, unsigned short* __restrict__ rwb,
    unsigned short* __restrict__ owb, unsigned short* __restrict__ gwb,
    unsigned short* __restrict__ wab, unsigned short* __restrict__ wbb,
    unsigned short* __restrict__ ub)
{
    int i4 = (blockIdx.x * 256 + threadIdx.x) * 4;
    const float* src; unsigned short* dst; int off;
    if      (i4 <  196608) { src = lw; dst = lwb; off = 0; }
    else if (i4 <  393216) { src = rw; dst = rwb; off = 196608; }
    else if (i4 <  409600) { src = ow; dst = owb; off = 393216; }
    else if (i4 < 1589248) { src = gw; dst = gwb; off = 409600; }
    else if (i4 < 1638400) { src = aw; dst = wab; off = 1589248; }
    else if (i4 < 1687552) { src = bw; dst = wbb; off = 1638400; }
    else if (i4 < 2080768) { src = sv; dst = ub;  off = 1687552; }
    else return;
    int j = i4 - off;
    float4 v = *(const float4*)&src[j];
    ushort4v p; p.x = f2b(v.x); p.y = f2b(v.y); p.z = f2b(v.z); p.w = f2b(v.w);
    *(ushort4v*)&dst[j] = p;
}

// ---------- left/right projections via MFMA (1 wave / 16x64 tile) ----------
// grid (BK/16, H/64, 2), block 64.
__global__ __launch_bounds__(64) void lr_mfma(
    const unsigned short* __restrict__ Ub,
    const unsigned short* __restrict__ lwb, const float* __restrict__ lb,
    const unsigned short* __restrict__ rwb, const float* __restrict__ rb,
    float* __restrict__ outL, float* __restrict__ outR)
{
    const int side = blockIdx.z;
    const unsigned short* __restrict__ W = side ? rwb : lwb;
    const float* __restrict__ bias = side ? rb : lb;
    float* __restrict__ out = side ? outR : outL;
    const int r0 = blockIdx.x * 16, n0 = blockIdx.y * 64;
    const int lane = threadIdx.x;
    const int col = lane & 15, quad = lane >> 4;
    const unsigned short* arow = &Ub[(size_t)(r0 + col)*D_ + quad*8];
    f32x4 acc[4] = {};
    #pragma unroll 4
    for (int kc = 0; kc < D_; kc += 32) {
        bf16x8 a = ldb(arow + kc);
        #pragma unroll
        for (int nt = 0; nt < 4; ++nt) {
            bf16x8 bb = ldb(&W[(size_t)(n0 + nt*16 + col)*D_ + kc + quad*8]);
            acc[nt] = __builtin_amdgcn_mfma_f32_16x16x32_bf16(a, bb, acc[nt], 0, 0, 0);
        }
    }
    #pragma unroll
    for (int nt = 0; nt < 4; ++nt) {
        const int n = n0 + nt*16 + col;
        const float bv = bias[n];
        #pragma unroll
        for (int r = 0; r < 4; ++r)
            out[(size_t)(r0 + quad*4 + r)*H_ + n] = acc[nt][r] + bv;
    }
}

// ---------- scores via MFMA, A-fragments built directly in registers ----------
// h[j,h] = relu(left[i,h] + right[j,h] + dist_emb[bkt(i,j),h]); S = h·out_w^T.
// Each thread owns A rows j=w*16+col, k-groups quad*8 within each 32-chunk.
// writeP: Pt[b][j][i][l] = bf16(sigmoid(S)*mask); else S fp32 (final call).
__global__ __launch_bounds__(256) void scores_mfma(
    const float* __restrict__ leftb, const float* __restrict__ rightb,
    const int* __restrict__ span_begin, const int* __restrict__ span_end,
    const float* __restrict__ dist_emb, const unsigned short* __restrict__ owb,
    const float* __restrict__ out_b, const float* __restrict__ mask,
    float* __restrict__ S, unsigned short* __restrict__ Pt, int writeP)
{
    const int j0 = blockIdx.x * 64;
    const int i  = blockIdx.y;
    const int b  = blockIdx.z;
    const int tid = threadIdx.x;
    __shared__ float sLeft[H_];
    __shared__ float sMask[64];
    __shared__ int sBkt[64];
    sLeft[tid] = leftb[(size_t)(b*K_ + i)*H_ + tid];
    if (tid < 64) {
        int d = span_begin[b*K_ + j0 + tid] - span_end[b*K_ + i];
        if (d < 0) d = -d;
        sBkt[tid] = d > 63 ? 63 : d;
        sMask[tid] = mask[(size_t)(b*K_ + i)*K_ + j0 + tid];
    }
    __syncthreads();

    const int w = tid >> 6, lane = tid & 63, col = lane & 15, quad = lane >> 4;
    const int jrow = w*16 + col;
    const float* rrow = &rightb[(size_t)(b*K_ + j0 + jrow)*H_ + quad*8];
    const float* drow = &dist_emb[(size_t)sBkt[jrow]*H_ + quad*8];
    const float* lptr = &sLeft[quad*8];

    bf16x8 afr[8];
    #pragma unroll
    for (int kc8 = 0; kc8 < 8; ++kc8) {
        const int base = kc8*32;
        float4 r0 = *(const float4*)&rrow[base];
        float4 r1 = *(const float4*)&rrow[base + 4];
        float4 d0 = *(const float4*)&drow[base];
        float4 d1 = *(const float4*)&drow[base + 4];
        ushort8 pk;
        pk[0] = f2b(fmaxf(0.f, lptr[base+0] + r0.x + d0.x));
        pk[1] = f2b(fmaxf(0.f, lptr[base+1] + r0.y + d0.y));
        pk[2] = f2b(fmaxf(0.f, lptr[base+2] + r0.z + d0.z));
        pk[3] = f2b(fmaxf(0.f, lptr[base+3] + r0.w + d0.w));
        pk[4] = f2b(fmaxf(0.f, lptr[base+4] + r1.x + d1.x));
        pk[5] = f2b(fmaxf(0.f, lptr[base+5] + r1.y + d1.y));
        pk[6] = f2b(fmaxf(0.f, lptr[base+6] + r1.z + d1.z));
        pk[7] = f2b(fmaxf(0.f, lptr[base+7] + r1.w + d1.w));
        afr[kc8] = __builtin_bit_cast(bf16x8, pk);
    }

    f32x4 acc[4] = {};
    #pragma unroll
    for (int kc8 = 0; kc8 < 8; ++kc8) {
        bf16x8 a = afr[kc8];
        #pragma unroll
        for (int nt = 0; nt < 4; ++nt) {
            bf16x8 bb = ldb(&owb[(size_t)(nt*16 + col)*H_ + kc8*32 + quad*8]);
            acc[nt] = __builtin_amdgcn_mfma_f32_16x16x32_bf16(a, bb, acc[nt], 0, 0, 0);
        }
    }
    #pragma unroll
    for (int nt = 0; nt < 4; ++nt) {
        const int l = nt*16 + col;
        const float ob = out_b[l];
        #pragma unroll
        for (int r = 0; r < 4; ++r) {
            const int jj = w*16 + quad*4 + r;   // C/D: row=quad*4+reg
            const int j = j0 + jj;
            const float v = acc[nt][r] + ob;
            if (writeP) {
                Pt[(((size_t)b*K_ + j)*K_ + i)*L_ + l] = f2b(sigm(v) * sMask[jj]);
            } else {
                S[(((size_t)b*K_ + i)*K_ + j)*L_ + l] = v;
            }
        }
    }
}

// ---------- ctxt via bf16 MFMA ----------
// C[b,m,d] += inv_len * sum_t u[t,d] * sum_l P(t,m)[l]*W[d,l]
// mode 0 (ctxt1): t=i, m=j, W=A_w -> P(t,m)=Pt[m][t]
// mode 1 (ctxt2): t=j, m=i, W=B_w -> P(t,m)=Pt[t][m]
__global__ __launch_bounds__(256) void ctxt_kernel(
    const unsigned short* __restrict__ Pt, const float* __restrict__ U,
    const unsigned short* __restrict__ WAb, const unsigned short* __restrict__ WBb,
    const float* __restrict__ lens, float* __restrict__ cacc)
{
    const int tid = threadIdx.x;
    const int bid = blockIdx.x;
    const int g = bid & 63;
    const int d0 = (bid >> 6) << 6;
    const int m0 = (g & 3) << 6;
    const int z = g >> 2;
    const int b = z >> 3;
    const int mode = (z >> 2) & 1;
    const int t0 = (z & 3) << 6;
    const unsigned short* __restrict__ Wb = mode ? WBb : WAb;

    const int lane = tid & 63, w = tid >> 6;
    const int col = lane & 15, quad = lane >> 4;

    __shared__ unsigned short sP[64][72];
    __shared__ float sU[64][68];

    {
        const int row = tid >> 2, cg = (tid & 3) * 16;
        const float* usrc = &U[((size_t)(b*K_ + t0 + row))*D_ + d0 + cg];
        #pragma unroll
        for (int u = 0; u < 4; ++u) {
            float4 v = *(const float4*)&usrc[u*4];
            *(float4*)&sU[row][cg + u*4] = v;
        }
    }
    bf16x8 bw[4][2];
    #pragma unroll
    for (int dt = 0; dt < 4; ++dt)
        #pragma unroll
        for (int kc = 0; kc < 2; ++kc)
            bw[dt][kc] = ldb(&Wb[(size_t)(d0 + dt*16 + col)*L_ + kc*32 + quad*8]);

    f32x4 acc[4] = {};
    const int lrow = tid >> 2, c16 = (tid & 3) * 16;
    const unsigned short* psrc0;
    size_t tstep;
    if (mode) {
        psrc0 = &Pt[(((size_t)b*K_ + t0)*K_ + m0 + lrow)*L_ + c16];
        tstep = (size_t)K_ * L_;
    } else {
        psrc0 = &Pt[(((size_t)b*K_ + m0 + lrow)*K_ + t0)*L_ + c16];
        tstep = (size_t)L_;
    }
    const int arow = w*16 + col;

    for (int t = 0; t < 64; ++t) {
        __syncthreads();
        {
            const unsigned short* src = psrc0 + (size_t)t * tstep;
            ushort8 v0 = *(const ushort8*)&src[0];
            ushort8 v1 = *(const ushort8*)&src[8];
            *(ushort8*)&sP[lrow][c16] = v0;
            *(ushort8*)&sP[lrow][c16 + 8] = v1;
        }
        __syncthreads();
        bf16x8 a0 = ldb(&sP[arow][quad*8]);
        bf16x8 a1 = ldb(&sP[arow][32 + quad*8]);
        #pragma unroll
        for (int dt = 0; dt < 4; ++dt) {
            f32x4 gacc = {0.f, 0.f, 0.f, 0.f};
            gacc = __builtin_amdgcn_mfma_f32_16x16x32_bf16(a0, bw[dt][0], gacc, 0, 0, 0);
            gacc = __builtin_amdgcn_mfma_f32_16x16x32_bf16(a1, bw[dt][1], gacc, 0, 0, 0);
            const float uu = sU[t][dt*16 + col];
            acc[dt] += gacc * uu;
        }
    }
    const float inv_len = 1.0f / lens[b];
    #pragma unroll
    for (int dt = 0; dt < 4; ++dt)
        #pragma unroll
        for (int r = 0; r < 4; ++r) {
            const int m = m0 + w*16 + quad*4 + r;
            atomicAdd(&cacc[((size_t)(b*K_) + m)*D_ + d0 + dt*16 + col],
                      acc[dt][r] * inv_len);
        }
}

// ---------- gate via MFMA (1 wave / 16x64 tile), cconv fused ----------
// logit = [Ub|f2b(C)]·gw^T; g=sigmoid(logit+gb); Unext = g*U + (1-g)*C.
// grid (BK/16, D/64), block 64.
__global__ __launch_bounds__(64) void gate_mfma(
    const unsigned short* __restrict__ Ub, const unsigned short* __restrict__ gwb,
    const float* __restrict__ gb,
    const float* __restrict__ Ucur, const float* __restrict__ Cc,
    float* __restrict__ Unext, unsigned short* __restrict__ Ubnext)
{
    const int r0 = blockIdx.x * 16, n0 = blockIdx.y * 64;
    const int lane = threadIdx.x;
    const int col = lane & 15, quad = lane >> 4;
    const unsigned short* arow_u = &Ub[(size_t)(r0 + col)*D_ + quad*8];
    const float* arow_c = &Cc[(size_t)(r0 + col)*D_ + quad*8];
    f32x4 acc[4] = {};
    #pragma unroll 4
    for (int kc = 0; kc < D_; kc += 32) {
        bf16x8 a = ldb(arow_u + kc);
        #pragma unroll
        for (int nt = 0; nt < 4; ++nt) {
            bf16x8 bb = ldb(&gwb[(size_t)(n0 + nt*16 + col)*(2*D_) + kc + quad*8]);
            acc[nt] = __builtin_amdgcn_mfma_f32_16x16x32_bf16(a, bb, acc[nt], 0, 0, 0);
        }
    }
    #pragma unroll 4
    for (int kc = 0; kc < D_; kc += 32) {
        bf16x8 a = cvt8(arow_c + kc);
        #pragma unroll
        for (int nt = 0; nt < 4; ++nt) {
            bf16x8 bb = ldb(&gwb[(size_t)(n0 + nt*16 + col)*(2*D_) + D_ + kc + quad*8]);
            acc[nt] = __builtin_amdgcn_mfma_f32_16x16x32_bf16(a, bb, acc[nt], 0, 0, 0);
        }
    }
    #pragma unroll
    for (int nt = 0; nt < 4; ++nt) {
        const int n = n0 + nt*16 + col;
        const float gbv = gb[n];
        #pragma unroll
        for (int r = 0; r < 4; ++r) {
            const size_t idx = (size_t)(r0 + quad*4 + r)*D_ + n;
            const float gg = sigm(acc[nt][r] + gbv);
            const float o = gg * Ucur[idx] + (1.f - gg) * Cc[idx];
            Unext[idx] = o;
            Ubnext[idx] = f2b(o);
        }
    }
}

// ---------- scatter updated rows into new_all ----------
__global__ __launch_bounds__(256) void scatter_kernel(
    const float* __restrict__ upd, const int* __restrict__ prune,
    const float* __restrict__ lens, float* __restrict__ out_all)
{
    const int blk = blockIdx.x;
    const int b = blk / K_, k = blk % K_;
    if ((float)k < lens[b]) {
        const int pi = prune[b*K_ + k];
        const int tid = threadIdx.x;
        if (tid < D_/4) {
            float4 v = *(const float4*)&upd[((size_t)b*K_ + k)*D_ + tid*4];
            *(float4*)&out_all[((size_t)b*N_ + pi)*D_ + tid*4] = v;
        }
    }
}

extern "C" void kernel_launch(void* const* d_in, const int* in_sizes, int n_in,
                              void* d_out, int out_size, void* d_ws, size_t ws_size,
                              hipStream_t stream) {
    (void)in_sizes; (void)n_in; (void)out_size; (void)ws_size;
    const float* all_span_vecs = (const float*)d_in[0];
    const float* span_vecs     = (const float*)d_in[1];
    const int*   span_begin    = (const int*)d_in[2];
    const int*   span_end      = (const int*)d_in[3];
    const float* mask          = (const float*)d_in[4];
    const float* lens          = (const float*)d_in[5];
    const int*   prune         = (const int*)d_in[6];
    const float* lw  = (const float*)d_in[7];
    const float* lb  = (const float*)d_in[8];
    const float* rw  = (const float*)d_in[9];
    const float* rb  = (const float*)d_in[10];
    const float* dist_emb = (const float*)d_in[11];
    const float* out_w    = (const float*)d_in[12];
    const float* out_b    = (const float*)d_in[13];
    const float* A_w = (const float*)d_in[14];
    const float* B_w = (const float*)d_in[15];
    const float* gw  = (const float*)d_in[16];
    const float* gb  = (const float*)d_in[17];

    float* out_all = (float*)d_out;
    float* out_upd = out_all + (size_t)B_*N_*D_;
    float* out_sc  = out_upd + (size_t)BK_*D_;

    float* ws     = (float*)d_ws;
    float* leftb  = ws;                       // BK*H
    float* rightb = leftb + (size_t)BK_*H_;   // BK*H
    float* U0     = rightb + (size_t)BK_*H_;  // BK*D
    float* U1     = U0 + (size_t)BK_*D_;      // BK*D
    float* cbuf   = U1 + (size_t)BK_*D_;      // BK*D
    unsigned short* WAb = (unsigned short*)(cbuf + (size_t)BK_*D_);
    unsigned short* WBb = WAb + (size_t)D_*L_;
    unsigned short* lwb = WBb + (size_t)D_*L_;
    unsigned short* rwb = lwb + (size_t)H_*D_;
    unsigned short* owb = rwb + (size_t)H_*D_;
    unsigned short* gwb = owb + (size_t)L_*H_;
    unsigned short* Ub0 = gwb + (size_t)D_*2*D_;
    unsigned short* Ub1 = Ub0 + (size_t)BK_*D_;
    unsigned short* Pt  = Ub1 + (size_t)BK_*D_;   // B*K*K*L bf16

    hipMemcpyAsync(out_all, all_span_vecs, sizeof(float)*(size_t)B_*N_*D_,
                   hipMemcpyDeviceToDevice, stream);

    dim3 blk256(256), blk64(64);
    conv_all<<<dim3(2032), blk256, 0, stream>>>(lw, rw, out_w, gw, A_w, B_w, span_vecs,
                                                lwb, rwb, owb, gwb, WAb, WBb, Ub0);
    lr_mfma<<<dim3(BK_/16, H_/64, 2), blk64, 0, stream>>>(Ub0, lwb, lb, rwb, rb, leftb, rightb);
    scores_mfma<<<dim3(K_/64, K_, B_), blk256, 0, stream>>>(leftb, rightb, span_begin, span_end,
                                                            dist_emb, owb, out_b, mask,
                                                            out_sc, Pt, 1);
    const float* Ucur = span_vecs;
    const unsigned short* Ubcur = Ub0;
    float* nexts[3] = {U0, U1, out_upd};
    unsigned short* nextsUb[3] = {Ub1, Ub0, Ub1};
    for (int it = 0; it < 3; ++it) {
        hipMemsetAsync(cbuf, 0, sizeof(float)*(size_t)BK_*D_, stream);
        ctxt_kernel<<<dim3(768), blk256, 0, stream>>>(Pt, Ucur, WAb, WBb, lens, cbuf);
        gate_mfma<<<dim3(BK_/16, D_/64), blk64, 0, stream>>>(Ubcur, gwb, gb,
                                                             Ucur, cbuf, nexts[it], nextsUb[it]);
        Ucur = nexts[it];
        Ubcur = nextsUb[it];
        lr_mfma<<<dim3(BK_/16, H_/64, 2), blk64, 0, stream>>>(Ubcur, lwb, lb, rwb, rb, leftb, rightb);
        scores_mfma<<<dim3(K_/64, K_, B_), blk256, 0, stream>>>(leftb, rightb, span_begin, span_end,
                                                                dist_emb, owb, out_b, mask,
                                                                out_sc, Pt, it == 2 ? 0 : 1);
    }
    scatter_kernel<<<dim3(BK_), blk256, 0, stream>>>(out_upd, prune, lens, out_all);
}

// Round 5
// 543.581 us; speedup vs baseline: 4.1091x; 1.0528x over previous
//
#include <hip/hip_runtime.h>

#define B_ 2
#define N_ 2048
#define K_ 256
#define D_ 768
#define H_ 256
#define L_ 64
#define BK_ (B_*K_)

typedef __attribute__((ext_vector_type(8))) __bf16 bf16x8;
typedef __attribute__((ext_vector_type(8))) unsigned short ushort8;
typedef __attribute__((ext_vector_type(4))) unsigned short ushort4v;
typedef __attribute__((ext_vector_type(4))) float f32x4;

__device__ __forceinline__ float sigm(float x) { return 1.0f / (1.0f + __expf(-x)); }

// round-to-nearest-even fp32 -> bf16
__device__ __forceinline__ unsigned short f2b(float f) {
    union { float f; unsigned int u; } v; v.f = f;
    unsigned int u = v.u;
    return (unsigned short)((u + 0x7FFFu + ((u >> 16) & 1u)) >> 16);
}
__device__ __forceinline__ bf16x8 ldb(const unsigned short* p) {
    ushort8 v = *(const ushort8*)p;
    return __builtin_bit_cast(bf16x8, v);
}
// load 8 fp32 -> bf16x8
__device__ __forceinline__ bf16x8 cvt8(const float* p) {
    float4 v0 = *(const float4*)p;
    float4 v1 = *(const float4*)(p + 4);
    ushort8 u;
    u[0] = f2b(v0.x); u[1] = f2b(v0.y); u[2] = f2b(v0.z); u[3] = f2b(v0.w);
    u[4] = f2b(v1.x); u[5] = f2b(v1.y); u[6] = f2b(v1.z); u[7] = f2b(v1.w);
    return __builtin_bit_cast(bf16x8, u);
}

// ---------- one-shot fp32->bf16 conversion of all static operands ----------
__global__ __launch_bounds__(256) void conv_all(
    const float* __restrict__ lw, const float* __restrict__ rw,
    const float* __restrict__ ow, const float* __restrict__ gw,
    const float* __restrict__ aw, const float* __restrict__ bw,
    const float* __restrict__ sv,
    unsigned short* __restrict__ lwb, unsigned short* __restrict__ rwb,
    unsigned short* __restrict__ owb, unsigned short* __restrict__ gwb,
    unsigned short* __restrict__ wab, unsigned short* __restrict__ wbb,
    unsigned short* __restrict__ ub)
{
    int i4 = (blockIdx.x * 256 + threadIdx.x) * 4;
    const float* src; unsigned short* dst; int off;
    if      (i4 <  196608) { src = lw; dst = lwb; off = 0; }
    else if (i4 <  393216) { src = rw; dst = rwb; off = 196608; }
    else if (i4 <  409600) { src = ow; dst = owb; off = 393216; }
    else if (i4 < 1589248) { src = gw; dst = gwb; off = 409600; }
    else if (i4 < 1638400) { src = aw; dst = wab; off = 1589248; }
    else if (i4 < 1687552) { src = bw; dst = wbb; off = 1638400; }
    else if (i4 < 2080768) { src = sv; dst = ub;  off = 1687552; }
    else return;
    int j = i4 - off;
    float4 v = *(const float4*)&src[j];
    ushort4v p; p.x = f2b(v.x); p.y = f2b(v.y); p.z = f2b(v.z); p.w = f2b(v.w);
    *(ushort4v*)&dst[j] = p;
}

// ---------- left/right projections via MFMA (1 wave / 16x64 tile) ----------
__global__ __launch_bounds__(64) void lr_mfma(
    const unsigned short* __restrict__ Ub,
    const unsigned short* __restrict__ lwb, const float* __restrict__ lb,
    const unsigned short* __restrict__ rwb, const float* __restrict__ rb,
    float* __restrict__ outL, float* __restrict__ outR)
{
    const int side = blockIdx.z;
    const unsigned short* __restrict__ W = side ? rwb : lwb;
    const float* __restrict__ bias = side ? rb : lb;
    float* __restrict__ out = side ? outR : outL;
    const int r0 = blockIdx.x * 16, n0 = blockIdx.y * 64;
    const int lane = threadIdx.x;
    const int col = lane & 15, quad = lane >> 4;
    const unsigned short* arow = &Ub[(size_t)(r0 + col)*D_ + quad*8];
    f32x4 acc[4] = {};
    #pragma unroll 4
    for (int kc = 0; kc < D_; kc += 32) {
        bf16x8 a = ldb(arow + kc);
        #pragma unroll
        for (int nt = 0; nt < 4; ++nt) {
            bf16x8 bb = ldb(&W[(size_t)(n0 + nt*16 + col)*D_ + kc + quad*8]);
            acc[nt] = __builtin_amdgcn_mfma_f32_16x16x32_bf16(a, bb, acc[nt], 0, 0, 0);
        }
    }
    #pragma unroll
    for (int nt = 0; nt < 4; ++nt) {
        const int n = n0 + nt*16 + col;
        const float bv = bias[n];
        #pragma unroll
        for (int r = 0; r < 4; ++r)
            out[(size_t)(r0 + quad*4 + r)*H_ + n] = acc[nt][r] + bv;
    }
}

// ---------- scores via MFMA, reg A-fragments, LDS-transposed coalesced stores ----
__global__ __launch_bounds__(256) void scores_mfma(
    const float* __restrict__ leftb, const float* __restrict__ rightb,
    const int* __restrict__ span_begin, const int* __restrict__ span_end,
    const float* __restrict__ dist_emb, const unsigned short* __restrict__ owb,
    const float* __restrict__ out_b, const float* __restrict__ mask,
    float* __restrict__ S, unsigned short* __restrict__ Pt, int writeP)
{
    const int j0 = blockIdx.x * 64;
    const int i  = blockIdx.y;
    const int b  = blockIdx.z;
    const int tid = threadIdx.x;
    __shared__ float sLeft[H_];
    __shared__ float sMask[64];
    __shared__ int sBkt[64];
    __shared__ float sT[64][68];   // [j][l] transpose buffer
    sLeft[tid] = leftb[(size_t)(b*K_ + i)*H_ + tid];
    if (tid < 64) {
        int d = span_begin[b*K_ + j0 + tid] - span_end[b*K_ + i];
        if (d < 0) d = -d;
        sBkt[tid] = d > 63 ? 63 : d;
        sMask[tid] = mask[(size_t)(b*K_ + i)*K_ + j0 + tid];
    }
    __syncthreads();

    const int w = tid >> 6, lane = tid & 63, col = lane & 15, quad = lane >> 4;
    const int jrow = w*16 + col;
    const float* rrow = &rightb[(size_t)(b*K_ + j0 + jrow)*H_ + quad*8];
    const float* drow = &dist_emb[(size_t)sBkt[jrow]*H_ + quad*8];
    const float* lptr = &sLeft[quad*8];

    bf16x8 afr[8];
    #pragma unroll
    for (int kc8 = 0; kc8 < 8; ++kc8) {
        const int base = kc8*32;
        float4 r0 = *(const float4*)&rrow[base];
        float4 r1 = *(const float4*)&rrow[base + 4];
        float4 d0 = *(const float4*)&drow[base];
        float4 d1 = *(const float4*)&drow[base + 4];
        ushort8 pk;
        pk[0] = f2b(fmaxf(0.f, lptr[base+0] + r0.x + d0.x));
        pk[1] = f2b(fmaxf(0.f, lptr[base+1] + r0.y + d0.y));
        pk[2] = f2b(fmaxf(0.f, lptr[base+2] + r0.z + d0.z));
        pk[3] = f2b(fmaxf(0.f, lptr[base+3] + r0.w + d0.w));
        pk[4] = f2b(fmaxf(0.f, lptr[base+4] + r1.x + d1.x));
        pk[5] = f2b(fmaxf(0.f, lptr[base+5] + r1.y + d1.y));
        pk[6] = f2b(fmaxf(0.f, lptr[base+6] + r1.z + d1.z));
        pk[7] = f2b(fmaxf(0.f, lptr[base+7] + r1.w + d1.w));
        afr[kc8] = __builtin_bit_cast(bf16x8, pk);
    }

    f32x4 acc[4] = {};
    #pragma unroll
    for (int kc8 = 0; kc8 < 8; ++kc8) {
        bf16x8 a = afr[kc8];
        #pragma unroll
        for (int nt = 0; nt < 4; ++nt) {
            bf16x8 bb = ldb(&owb[(size_t)(nt*16 + col)*H_ + kc8*32 + quad*8]);
            acc[nt] = __builtin_amdgcn_mfma_f32_16x16x32_bf16(a, bb, acc[nt], 0, 0, 0);
        }
    }
    // transpose through LDS: sT[j][l] = acc + out_b
    #pragma unroll
    for (int nt = 0; nt < 4; ++nt) {
        const int l = nt*16 + col;
        const float ob = out_b[l];
        #pragma unroll
        for (int r = 0; r < 4; ++r)
            sT[w*16 + quad*4 + r][l] = acc[nt][r] + ob;
    }
    __syncthreads();
    // coalesced stores: thread -> j = tid>>2, l-segment = (tid&3)*16
    const int jj = tid >> 2, seg = (tid & 3) * 16;
    const int j = j0 + jj;
    if (writeP) {
        const float msk = sMask[jj];
        ushort8 o0, o1;
        #pragma unroll
        for (int e = 0; e < 8; ++e) {
            o0[e] = f2b(sigm(sT[jj][seg + e]) * msk);
            o1[e] = f2b(sigm(sT[jj][seg + 8 + e]) * msk);
        }
        unsigned short* dst = &Pt[(((size_t)b*K_ + j)*K_ + i)*L_ + seg];
        *(ushort8*)&dst[0] = o0;
        *(ushort8*)&dst[8] = o1;
    } else {
        float* dst = &S[(((size_t)b*K_ + i)*K_ + j)*L_ + seg];
        #pragma unroll
        for (int q = 0; q < 4; ++q) {
            float4 v;
            v.x = sT[jj][seg + q*4 + 0];
            v.y = sT[jj][seg + q*4 + 1];
            v.z = sT[jj][seg + q*4 + 2];
            v.w = sT[jj][seg + q*4 + 3];
            *(float4*)&dst[q*4] = v;
        }
    }
}

// ---------- ctxt via bf16 MFMA, software-pipelined P staging ----------
// C[b,m,d] += inv_len * sum_t u[t,d] * sum_l P(t,m)[l]*W[d,l]
// mode 0 (ctxt1): t=i, m=j, W=A_w -> P(t,m)=Pt[m][t]
// mode 1 (ctxt2): t=j, m=i, W=B_w -> P(t,m)=Pt[t][m]
__global__ __launch_bounds__(256) void ctxt_kernel(
    const unsigned short* __restrict__ Pt, const float* __restrict__ U,
    const unsigned short* __restrict__ WAb, const unsigned short* __restrict__ WBb,
    const float* __restrict__ lens, float* __restrict__ cacc)
{
    const int tid = threadIdx.x;
    const int bid = blockIdx.x;
    const int g = bid & 63;
    const int d0 = (bid >> 6) << 6;
    const int m0 = (g & 3) << 6;
    const int z = g >> 2;
    const int b = z >> 3;
    const int mode = (z >> 2) & 1;
    const int t0 = (z & 3) << 6;
    const unsigned short* __restrict__ Wb = mode ? WBb : WAb;

    const int lane = tid & 63, w = tid >> 6;
    const int col = lane & 15, quad = lane >> 4;

    __shared__ unsigned short sP[2][64][72];
    __shared__ float sU[64][68];

    {
        const int row = tid >> 2, cg = (tid & 3) * 16;
        const float* usrc = &U[((size_t)(b*K_ + t0 + row))*D_ + d0 + cg];
        #pragma unroll
        for (int u = 0; u < 4; ++u) {
            float4 v = *(const float4*)&usrc[u*4];
            *(float4*)&sU[row][cg + u*4] = v;
        }
    }
    bf16x8 bw[4][2];
    #pragma unroll
    for (int dt = 0; dt < 4; ++dt)
        #pragma unroll
        for (int kc = 0; kc < 2; ++kc)
            bw[dt][kc] = ldb(&Wb[(size_t)(d0 + dt*16 + col)*L_ + kc*32 + quad*8]);

    f32x4 acc[4] = {};
    const int lrow = tid >> 2, c16 = (tid & 3) * 16;
    const unsigned short* psrc0;
    size_t tstep;
    if (mode) {
        psrc0 = &Pt[(((size_t)b*K_ + t0)*K_ + m0 + lrow)*L_ + c16];
        tstep = (size_t)K_ * L_;
    } else {
        psrc0 = &Pt[(((size_t)b*K_ + m0 + lrow)*K_ + t0)*L_ + c16];
        tstep = (size_t)L_;
    }
    const int arow = w*16 + col;

    ushort8 v0 = *(const ushort8*)&psrc0[0];
    ushort8 v1 = *(const ushort8*)&psrc0[8];
    for (int t = 0; t < 64; ++t) {
        unsigned short (*buf)[72] = sP[t & 1];
        *(ushort8*)&buf[lrow][c16] = v0;
        *(ushort8*)&buf[lrow][c16 + 8] = v1;
        if (t < 63) {
            const unsigned short* src = psrc0 + (size_t)(t + 1) * tstep;
            v0 = *(const ushort8*)&src[0];
            v1 = *(const ushort8*)&src[8];
        }
        __syncthreads();
        bf16x8 a0 = ldb(&buf[arow][quad*8]);
        bf16x8 a1 = ldb(&buf[arow][32 + quad*8]);
        #pragma unroll
        for (int dt = 0; dt < 4; ++dt) {
            f32x4 gacc = {0.f, 0.f, 0.f, 0.f};
            gacc = __builtin_amdgcn_mfma_f32_16x16x32_bf16(a0, bw[dt][0], gacc, 0, 0, 0);
            gacc = __builtin_amdgcn_mfma_f32_16x16x32_bf16(a1, bw[dt][1], gacc, 0, 0, 0);
            const float uu = sU[t][dt*16 + col];
            acc[dt] += gacc * uu;
        }
    }
    const float inv_len = 1.0f / lens[b];
    #pragma unroll
    for (int dt = 0; dt < 4; ++dt)
        #pragma unroll
        for (int r = 0; r < 4; ++r) {
            const int m = m0 + w*16 + quad*4 + r;
            atomicAdd(&cacc[((size_t)(b*K_) + m)*D_ + d0 + dt*16 + col],
                      acc[dt][r] * inv_len);
        }
}

// ---------- gate via MFMA (1 wave / 16x64 tile), cconv fused ----------
__global__ __launch_bounds__(64) void gate_mfma(
    const unsigned short* __restrict__ Ub, const unsigned short* __restrict__ gwb,
    const float* __restrict__ gb,
    const float* __restrict__ Ucur, const float* __restrict__ Cc,
    float* __restrict__ Unext, unsigned short* __restrict__ Ubnext)
{
    const int r0 = blockIdx.x * 16, n0 = blockIdx.y * 64;
    const int lane = threadIdx.x;
    const int col = lane & 15, quad = lane >> 4;
    const unsigned short* arow_u = &Ub[(size_t)(r0 + col)*D_ + quad*8];
    const float* arow_c = &Cc[(size_t)(r0 + col)*D_ + quad*8];
    f32x4 acc[4] = {};
    #pragma unroll 4
    for (int kc = 0; kc < D_; kc += 32) {
        bf16x8 a = ldb(arow_u + kc);
        #pragma unroll
        for (int nt = 0; nt < 4; ++nt) {
            bf16x8 bb = ldb(&gwb[(size_t)(n0 + nt*16 + col)*(2*D_) + kc + quad*8]);
            acc[nt] = __builtin_amdgcn_mfma_f32_16x16x32_bf16(a, bb, acc[nt], 0, 0, 0);
        }
    }
    #pragma unroll 4
    for (int kc = 0; kc < D_; kc += 32) {
        bf16x8 a = cvt8(arow_c + kc);
        #pragma unroll
        for (int nt = 0; nt < 4; ++nt) {
            bf16x8 bb = ldb(&gwb[(size_t)(n0 + nt*16 + col)*(2*D_) + D_ + kc + quad*8]);
            acc[nt] = __builtin_amdgcn_mfma_f32_16x16x32_bf16(a, bb, acc[nt], 0, 0, 0);
        }
    }
    #pragma unroll
    for (int nt = 0; nt < 4; ++nt) {
        const int n = n0 + nt*16 + col;
        const float gbv = gb[n];
        #pragma unroll
        for (int r = 0; r < 4; ++r) {
            const size_t idx = (size_t)(r0 + quad*4 + r)*D_ + n;
            const float gg = sigm(acc[nt][r] + gbv);
            const float o = gg * Ucur[idx] + (1.f - gg) * Cc[idx];
            Unext[idx] = o;
            Ubnext[idx] = f2b(o);
        }
    }
}

// ---------- scatter updated rows into new_all ----------
__global__ __launch_bounds__(256) void scatter_kernel(
    const float* __restrict__ upd, const int* __restrict__ prune,
    const float* __restrict__ lens, float* __restrict__ out_all)
{
    const int blk = blockIdx.x;
    const int b = blk / K_, k = blk % K_;
    if ((float)k < lens[b]) {
        const int pi = prune[b*K_ + k];
        const int tid = threadIdx.x;
        if (tid < D_/4) {
            float4 v = *(const float4*)&upd[((size_t)b*K_ + k)*D_ + tid*4];
            *(float4*)&out_all[((size_t)b*N_ + pi)*D_ + tid*4] = v;
        }
    }
}

extern "C" void kernel_launch(void* const* d_in, const int* in_sizes, int n_in,
                              void* d_out, int out_size, void* d_ws, size_t ws_size,
                              hipStream_t stream) {
    (void)in_sizes; (void)n_in; (void)out_size; (void)ws_size;
    const float* all_span_vecs = (const float*)d_in[0];
    const float* span_vecs     = (const float*)d_in[1];
    const int*   span_begin    = (const int*)d_in[2];
    const int*   span_end      = (const int*)d_in[3];
    const float* mask          = (const float*)d_in[4];
    const float* lens          = (const float*)d_in[5];
    const int*   prune         = (const int*)d_in[6];
    const float* lw  = (const float*)d_in[7];
    const float* lb  = (const float*)d_in[8];
    const float* rw  = (const float*)d_in[9];
    const float* rb  = (const float*)d_in[10];
    const float* dist_emb = (const float*)d_in[11];
    const float* out_w    = (const float*)d_in[12];
    const float* out_b    = (const float*)d_in[13];
    const float* A_w = (const float*)d_in[14];
    const float* B_w = (const float*)d_in[15];
    const float* gw  = (const float*)d_in[16];
    const float* gb  = (const float*)d_in[17];

    float* out_all = (float*)d_out;
    float* out_upd = out_all + (size_t)B_*N_*D_;
    float* out_sc  = out_upd + (size_t)BK_*D_;

    float* ws     = (float*)d_ws;
    float* leftb  = ws;                       // BK*H
    float* rightb = leftb + (size_t)BK_*H_;   // BK*H
    float* U0     = rightb + (size_t)BK_*H_;  // BK*D
    float* U1     = U0 + (size_t)BK_*D_;      // BK*D
    float* cbuf   = U1 + (size_t)BK_*D_;      // BK*D
    unsigned short* WAb = (unsigned short*)(cbuf + (size_t)BK_*D_);
    unsigned short* WBb = WAb + (size_t)D_*L_;
    unsigned short* lwb = WBb + (size_t)D_*L_;
    unsigned short* rwb = lwb + (size_t)H_*D_;
    unsigned short* owb = rwb + (size_t)H_*D_;
    unsigned short* gwb = owb + (size_t)L_*H_;
    unsigned short* Ub0 = gwb + (size_t)D_*2*D_;
    unsigned short* Ub1 = Ub0 + (size_t)BK_*D_;
    unsigned short* Pt  = Ub1 + (size_t)BK_*D_;   // B*K*K*L bf16

    hipMemcpyAsync(out_all, all_span_vecs, sizeof(float)*(size_t)B_*N_*D_,
                   hipMemcpyDeviceToDevice, stream);

    dim3 blk256(256), blk64(64);
    conv_all<<<dim3(2032), blk256, 0, stream>>>(lw, rw, out_w, gw, A_w, B_w, span_vecs,
                                                lwb, rwb, owb, gwb, WAb, WBb, Ub0);
    lr_mfma<<<dim3(BK_/16, H_/64, 2), blk64, 0, stream>>>(Ub0, lwb, lb, rwb, rb, leftb, rightb);
    scores_mfma<<<dim3(K_/64, K_, B_), blk256, 0, stream>>>(leftb, rightb, span_begin, span_end,
                                                            dist_emb, owb, out_b, mask,
                                                            out_sc, Pt, 1);
    const float* Ucur = span_vecs;
    const unsigned short* Ubcur = Ub0;
    float* nexts[3] = {U0, U1, out_upd};
    unsigned short* nextsUb[3] = {Ub1, Ub0, Ub1};
    for (int it = 0; it < 3; ++it) {
        hipMemsetAsync(cbuf, 0, sizeof(float)*(size_t)BK_*D_, stream);
        ctxt_kernel<<<dim3(768), blk256, 0, stream>>>(Pt, Ucur, WAb, WBb, lens, cbuf);
        gate_mfma<<<dim3(BK_/16, D_/64), blk64, 0, stream>>>(Ubcur, gwb, gb,
                                                             Ucur, cbuf, nexts[it], nextsUb[it]);
        Ucur = nexts[it];
        Ubcur = nextsUb[it];
        lr_mfma<<<dim3(BK_/16, H_/64, 2), blk64, 0, stream>>>(Ubcur, lwb, lb, rwb, rb, leftb, rightb);
        scores_mfma<<<dim3(K_/64, K_, B_), blk256, 0, stream>>>(leftb, rightb, span_begin, span_end,
                                                                dist_emb, owb, out_b, mask,
                                                                out_sc, Pt, it == 2 ? 0 : 1);
    }
    scatter_kernel<<<dim3(BK_), blk256, 0, stream>>>(out_upd, prune, lens, out_all);
}

// Round 6
// 443.209 us; speedup vs baseline: 5.0397x; 1.2265x over previous
//
#include <hip/hip_runtime.h>

#define B_ 2
#define N_ 2048
#define K_ 256
#define D_ 768
#define H_ 256
#define L_ 64
#define BK_ (B_*K_)

typedef __attribute__((ext_vector_type(8))) __bf16 bf16x8;
typedef __attribute__((ext_vector_type(8))) unsigned short ushort8;
typedef __attribute__((ext_vector_type(4))) unsigned short ushort4v;
typedef __attribute__((ext_vector_type(4))) float f32x4;

__device__ __forceinline__ float sigm(float x) { return 1.0f / (1.0f + __expf(-x)); }

// round-to-nearest-even fp32 -> bf16
__device__ __forceinline__ unsigned short f2b(float f) {
    union { float f; unsigned int u; } v; v.f = f;
    unsigned int u = v.u;
    return (unsigned short)((u + 0x7FFFu + ((u >> 16) & 1u)) >> 16);
}
__device__ __forceinline__ float b2f(unsigned short us) {
    union { unsigned int u; float f; } v; v.u = ((unsigned int)us) << 16;
    return v.f;
}
__device__ __forceinline__ bf16x8 ldb(const unsigned short* p) {
    ushort8 v = *(const ushort8*)p;
    return __builtin_bit_cast(bf16x8, v);
}
// load 8 fp32 -> bf16x8
__device__ __forceinline__ bf16x8 cvt8(const float* p) {
    float4 v0 = *(const float4*)p;
    float4 v1 = *(const float4*)(p + 4);
    ushort8 u;
    u[0] = f2b(v0.x); u[1] = f2b(v0.y); u[2] = f2b(v0.z); u[3] = f2b(v0.w);
    u[4] = f2b(v1.x); u[5] = f2b(v1.y); u[6] = f2b(v1.z); u[7] = f2b(v1.w);
    return __builtin_bit_cast(bf16x8, u);
}

// ---------- one-shot fp32->bf16 conversion of all static operands ----------
// lw,rw (H*D), out_w (L*H), gw (D*2D), A_w,B_w (D*L), span_vecs (BK*D), dist_emb (64*H)
__global__ __launch_bounds__(256) void conv_all(
    const float* __restrict__ lw, const float* __restrict__ rw,
    const float* __restrict__ ow, const float* __restrict__ gw,
    const float* __restrict__ aw, const float* __restrict__ bw,
    const float* __restrict__ sv, const float* __restrict__ de,
    unsigned short* __restrict__ lwb, unsigned short* __restrict__ rwb,
    unsigned short* __restrict__ owb, unsigned short* __restrict__ gwb,
    unsigned short* __restrict__ wab, unsigned short* __restrict__ wbb,
    unsigned short* __restrict__ ub, unsigned short* __restrict__ deb)
{
    int i4 = (blockIdx.x * 256 + threadIdx.x) * 4;
    const float* src; unsigned short* dst; int off;
    if      (i4 <  196608) { src = lw; dst = lwb; off = 0; }
    else if (i4 <  393216) { src = rw; dst = rwb; off = 196608; }
    else if (i4 <  409600) { src = ow; dst = owb; off = 393216; }
    else if (i4 < 1589248) { src = gw; dst = gwb; off = 409600; }
    else if (i4 < 1638400) { src = aw; dst = wab; off = 1589248; }
    else if (i4 < 1687552) { src = bw; dst = wbb; off = 1638400; }
    else if (i4 < 2080768) { src = sv; dst = ub;  off = 1687552; }
    else if (i4 < 2097152) { src = de; dst = deb; off = 2080768; }
    else return;
    int j = i4 - off;
    float4 v = *(const float4*)&src[j];
    ushort4v p; p.x = f2b(v.x); p.y = f2b(v.y); p.z = f2b(v.z); p.w = f2b(v.w);
    *(ushort4v*)&dst[j] = p;
}

// ---------- left/right projections via MFMA (1 wave / 16x64 tile) ----------
// side 0: left -> fp32 outL.  side 1: right -> bf16 outRb.
__global__ __launch_bounds__(64) void lr_mfma(
    const unsigned short* __restrict__ Ub,
    const unsigned short* __restrict__ lwb, const float* __restrict__ lb,
    const unsigned short* __restrict__ rwb, const float* __restrict__ rb,
    float* __restrict__ outL, unsigned short* __restrict__ outRb)
{
    const int side = blockIdx.z;
    const unsigned short* __restrict__ W = side ? rwb : lwb;
    const float* __restrict__ bias = side ? rb : lb;
    const int r0 = blockIdx.x * 16, n0 = blockIdx.y * 64;
    const int lane = threadIdx.x;
    const int col = lane & 15, quad = lane >> 4;
    const unsigned short* arow = &Ub[(size_t)(r0 + col)*D_ + quad*8];
    f32x4 acc[4] = {};
    #pragma unroll 4
    for (int kc = 0; kc < D_; kc += 32) {
        bf16x8 a = ldb(arow + kc);
        #pragma unroll
        for (int nt = 0; nt < 4; ++nt) {
            bf16x8 bb = ldb(&W[(size_t)(n0 + nt*16 + col)*D_ + kc + quad*8]);
            acc[nt] = __builtin_amdgcn_mfma_f32_16x16x32_bf16(a, bb, acc[nt], 0, 0, 0);
        }
    }
    #pragma unroll
    for (int nt = 0; nt < 4; ++nt) {
        const int n = n0 + nt*16 + col;
        const float bv = bias[n];
        #pragma unroll
        for (int r = 0; r < 4; ++r) {
            const size_t idx = (size_t)(r0 + quad*4 + r)*H_ + n;
            if (side) outRb[idx] = f2b(acc[nt][r] + bv);
            else      outL[idx] = acc[nt][r] + bv;
        }
    }
}

// ---------- scores v6: 8i x 64j tile per block, LDS right/left, reg-resident owb ----
// h[j,h] = relu(left[i,h] + right_bf[j,h] + dist_bf[bkt(i,j),h]); S = h·out_w^T.
// grid (K/64=4, K/8=32, B=2) = 256 blocks, 256 threads.
__global__ __launch_bounds__(256, 1) void scores_v6(
    const float* __restrict__ leftb, const unsigned short* __restrict__ rbb,
    const int* __restrict__ span_begin, const int* __restrict__ span_end,
    const unsigned short* __restrict__ deb, const unsigned short* __restrict__ owb,
    const float* __restrict__ out_b, const float* __restrict__ mask,
    float* __restrict__ S, unsigned short* __restrict__ Pt, int writeP)
{
    const int j0 = blockIdx.x * 64;
    const int i0 = blockIdx.y * 8;
    const int b  = blockIdx.z;
    const int tid = threadIdx.x;
    const int w = tid >> 6, lane = tid & 63, col = lane & 15, quad = lane >> 4;
    const int jrow = w*16 + col;

    __shared__ unsigned short sR[64][264];  // right j-tile bf16, padded rows
    __shared__ float sL[8][256];            // left i-tile fp32
    __shared__ float sT[64][68];            // per-i transpose buffer
    __shared__ float sMask[8][64];
    __shared__ int   sBkt[8][64];

    // buckets + mask (512 pairs)
    #pragma unroll
    for (int q = 0; q < 2; ++q) {
        int p = tid + q*256;
        int ii = p >> 6, jj = p & 63;
        int d = span_begin[b*K_ + j0 + jj] - span_end[b*K_ + i0 + ii];
        if (d < 0) d = -d;
        sBkt[ii][jj] = d > 63 ? 63 : d;
        sMask[ii][jj] = mask[(size_t)(b*K_ + i0 + ii)*K_ + j0 + jj];
    }
    // left tile: 512 float4s
    #pragma unroll
    for (int q = 0; q < 2; ++q) {
        int f = tid + q*256;
        int row = f >> 6, c4 = (f & 63) * 4;
        *(float4*)&sL[row][c4] = *(const float4*)&leftb[(size_t)(b*K_ + i0 + row)*H_ + c4];
    }
    // right tile: 2048 16B chunks
    #pragma unroll
    for (int q = 0; q < 8; ++q) {
        int c = tid + q*256;
        int row = c >> 5, ch = c & 31;
        *(ushort8*)&sR[row][ch*8] = *(const ushort8*)&rbb[(size_t)(b*K_ + j0 + row)*H_ + ch*8];
    }
    // persistent B-fragments (out_w): 128 VGPRs
    bf16x8 bb[4][8];
    #pragma unroll
    for (int lt = 0; lt < 4; ++lt)
        #pragma unroll
        for (int k = 0; k < 8; ++k)
            bb[lt][k] = ldb(&owb[(size_t)(lt*16 + col)*H_ + k*32 + quad*8]);
    float ob[4];
    #pragma unroll
    for (int lt = 0; lt < 4; ++lt) ob[lt] = out_b[lt*16 + col];
    __syncthreads();

    for (int i = 0; i < 8; ++i) {
        const int bkt = sBkt[i][jrow];
        const unsigned short* dr = &deb[(size_t)bkt*H_ + quad*8];
        const float* lrow = &sL[i][quad*8];
        f32x4 acc[4] = {};
        #pragma unroll
        for (int k = 0; k < 8; ++k) {
            float4 l0 = *(const float4*)&lrow[k*32];
            float4 l1 = *(const float4*)&lrow[k*32 + 4];
            ushort8 rv = *(const ushort8*)&sR[jrow][k*32 + quad*8];
            ushort8 dv = *(const ushort8*)&dr[k*32];
            ushort8 pk;
            pk[0] = f2b(fmaxf(0.f, l0.x + b2f(rv[0]) + b2f(dv[0])));
            pk[1] = f2b(fmaxf(0.f, l0.y + b2f(rv[1]) + b2f(dv[1])));
            pk[2] = f2b(fmaxf(0.f, l0.z + b2f(rv[2]) + b2f(dv[2])));
            pk[3] = f2b(fmaxf(0.f, l0.w + b2f(rv[3]) + b2f(dv[3])));
            pk[4] = f2b(fmaxf(0.f, l1.x + b2f(rv[4]) + b2f(dv[4])));
            pk[5] = f2b(fmaxf(0.f, l1.y + b2f(rv[5]) + b2f(dv[5])));
            pk[6] = f2b(fmaxf(0.f, l1.z + b2f(rv[6]) + b2f(dv[6])));
            pk[7] = f2b(fmaxf(0.f, l1.w + b2f(rv[7]) + b2f(dv[7])));
            bf16x8 a = __builtin_bit_cast(bf16x8, pk);
            #pragma unroll
            for (int lt = 0; lt < 4; ++lt)
                acc[lt] = __builtin_amdgcn_mfma_f32_16x16x32_bf16(a, bb[lt][k], acc[lt], 0, 0, 0);
        }
        __syncthreads();   // prior i's sT reads done
        #pragma unroll
        for (int lt = 0; lt < 4; ++lt)
            #pragma unroll
            for (int r = 0; r < 4; ++r)
                sT[w*16 + quad*4 + r][lt*16 + col] = acc[lt][r] + ob[lt];
        __syncthreads();
        const int jj = tid >> 2, seg = (tid & 3) * 16;
        const int j = j0 + jj, ii = i0 + i;
        if (writeP) {
            const float msk = sMask[i][jj];
            ushort8 o0, o1;
            #pragma unroll
            for (int e = 0; e < 8; ++e) {
                o0[e] = f2b(sigm(sT[jj][seg + e]) * msk);
                o1[e] = f2b(sigm(sT[jj][seg + 8 + e]) * msk);
            }
            unsigned short* dst = &Pt[(((size_t)b*K_ + j)*K_ + ii)*L_ + seg];
            *(ushort8*)&dst[0] = o0;
            *(ushort8*)&dst[8] = o1;
        } else {
            float* dst = &S[(((size_t)b*K_ + ii)*K_ + j)*L_ + seg];
            #pragma unroll
            for (int q2 = 0; q2 < 4; ++q2) {
                float4 v;
                v.x = sT[jj][seg + q2*4 + 0];
                v.y = sT[jj][seg + q2*4 + 1];
                v.z = sT[jj][seg + q2*4 + 2];
                v.w = sT[jj][seg + q2*4 + 3];
                *(float4*)&dst[q2*4] = v;
            }
        }
    }
}

// ---------- ctxt via bf16 MFMA, software-pipelined P staging ----------
__global__ __launch_bounds__(256) void ctxt_kernel(
    const unsigned short* __restrict__ Pt, const float* __restrict__ U,
    const unsigned short* __restrict__ WAb, const unsigned short* __restrict__ WBb,
    const float* __restrict__ lens, float* __restrict__ cacc)
{
    const int tid = threadIdx.x;
    const int bid = blockIdx.x;
    const int g = bid & 63;
    const int d0 = (bid >> 6) << 6;
    const int m0 = (g & 3) << 6;
    const int z = g >> 2;
    const int b = z >> 3;
    const int mode = (z >> 2) & 1;
    const int t0 = (z & 3) << 6;
    const unsigned short* __restrict__ Wb = mode ? WBb : WAb;

    const int lane = tid & 63, w = tid >> 6;
    const int col = lane & 15, quad = lane >> 4;

    __shared__ unsigned short sP[2][64][72];
    __shared__ float sU[64][68];

    {
        const int row = tid >> 2, cg = (tid & 3) * 16;
        const float* usrc = &U[((size_t)(b*K_ + t0 + row))*D_ + d0 + cg];
        #pragma unroll
        for (int u = 0; u < 4; ++u) {
            float4 v = *(const float4*)&usrc[u*4];
            *(float4*)&sU[row][cg + u*4] = v;
        }
    }
    bf16x8 bw[4][2];
    #pragma unroll
    for (int dt = 0; dt < 4; ++dt)
        #pragma unroll
        for (int kc = 0; kc < 2; ++kc)
            bw[dt][kc] = ldb(&Wb[(size_t)(d0 + dt*16 + col)*L_ + kc*32 + quad*8]);

    f32x4 acc[4] = {};
    const int lrow = tid >> 2, c16 = (tid & 3) * 16;
    const unsigned short* psrc0;
    size_t tstep;
    if (mode) {
        psrc0 = &Pt[(((size_t)b*K_ + t0)*K_ + m0 + lrow)*L_ + c16];
        tstep = (size_t)K_ * L_;
    } else {
        psrc0 = &Pt[(((size_t)b*K_ + m0 + lrow)*K_ + t0)*L_ + c16];
        tstep = (size_t)L_;
    }
    const int arow = w*16 + col;

    ushort8 v0 = *(const ushort8*)&psrc0[0];
    ushort8 v1 = *(const ushort8*)&psrc0[8];
    for (int t = 0; t < 64; ++t) {
        unsigned short (*buf)[72] = sP[t & 1];
        *(ushort8*)&buf[lrow][c16] = v0;
        *(ushort8*)&buf[lrow][c16 + 8] = v1;
        if (t < 63) {
            const unsigned short* src = psrc0 + (size_t)(t + 1) * tstep;
            v0 = *(const ushort8*)&src[0];
            v1 = *(const ushort8*)&src[8];
        }
        __syncthreads();
        bf16x8 a0 = ldb(&buf[arow][quad*8]);
        bf16x8 a1 = ldb(&buf[arow][32 + quad*8]);
        #pragma unroll
        for (int dt = 0; dt < 4; ++dt) {
            f32x4 gacc = {0.f, 0.f, 0.f, 0.f};
            gacc = __builtin_amdgcn_mfma_f32_16x16x32_bf16(a0, bw[dt][0], gacc, 0, 0, 0);
            gacc = __builtin_amdgcn_mfma_f32_16x16x32_bf16(a1, bw[dt][1], gacc, 0, 0, 0);
            const float uu = sU[t][dt*16 + col];
            acc[dt] += gacc * uu;
        }
    }
    const float inv_len = 1.0f / lens[b];
    #pragma unroll
    for (int dt = 0; dt < 4; ++dt)
        #pragma unroll
        for (int r = 0; r < 4; ++r) {
            const int m = m0 + w*16 + quad*4 + r;
            atomicAdd(&cacc[((size_t)(b*K_) + m)*D_ + d0 + dt*16 + col],
                      acc[dt][r] * inv_len);
        }
}

// ---------- gate via MFMA (1 wave / 16x64 tile), cconv fused ----------
__global__ __launch_bounds__(64) void gate_mfma(
    const unsigned short* __restrict__ Ub, const unsigned short* __restrict__ gwb,
    const float* __restrict__ gb,
    const float* __restrict__ Ucur, const float* __restrict__ Cc,
    float* __restrict__ Unext, unsigned short* __restrict__ Ubnext)
{
    const int r0 = blockIdx.x * 16, n0 = blockIdx.y * 64;
    const int lane = threadIdx.x;
    const int col = lane & 15, quad = lane >> 4;
    const unsigned short* arow_u = &Ub[(size_t)(r0 + col)*D_ + quad*8];
    const float* arow_c = &Cc[(size_t)(r0 + col)*D_ + quad*8];
    f32x4 acc[4] = {};
    #pragma unroll 4
    for (int kc = 0; kc < D_; kc += 32) {
        bf16x8 a = ldb(arow_u + kc);
        #pragma unroll
        for (int nt = 0; nt < 4; ++nt) {
            bf16x8 bb = ldb(&gwb[(size_t)(n0 + nt*16 + col)*(2*D_) + kc + quad*8]);
            acc[nt] = __builtin_amdgcn_mfma_f32_16x16x32_bf16(a, bb, acc[nt], 0, 0, 0);
        }
    }
    #pragma unroll 4
    for (int kc = 0; kc < D_; kc += 32) {
        bf16x8 a = cvt8(arow_c + kc);
        #pragma unroll
        for (int nt = 0; nt < 4; ++nt) {
            bf16x8 bb = ldb(&gwb[(size_t)(n0 + nt*16 + col)*(2*D_) + D_ + kc + quad*8]);
            acc[nt] = __builtin_amdgcn_mfma_f32_16x16x32_bf16(a, bb, acc[nt], 0, 0, 0);
        }
    }
    #pragma unroll
    for (int nt = 0; nt < 4; ++nt) {
        const int n = n0 + nt*16 + col;
        const float gbv = gb[n];
        #pragma unroll
        for (int r = 0; r < 4; ++r) {
            const size_t idx = (size_t)(r0 + quad*4 + r)*D_ + n;
            const float gg = sigm(acc[nt][r] + gbv);
            const float o = gg * Ucur[idx] + (1.f - gg) * Cc[idx];
            Unext[idx] = o;
            Ubnext[idx] = f2b(o);
        }
    }
}

// ---------- scatter updated rows into new_all ----------
__global__ __launch_bounds__(256) void scatter_kernel(
    const float* __restrict__ upd, const int* __restrict__ prune,
    const float* __restrict__ lens, float* __restrict__ out_all)
{
    const int blk = blockIdx.x;
    const int b = blk / K_, k = blk % K_;
    if ((float)k < lens[b]) {
        const int pi = prune[b*K_ + k];
        const int tid = threadIdx.x;
        if (tid < D_/4) {
            float4 v = *(const float4*)&upd[((size_t)b*K_ + k)*D_ + tid*4];
            *(float4*)&out_all[((size_t)b*N_ + pi)*D_ + tid*4] = v;
        }
    }
}

extern "C" void kernel_launch(void* const* d_in, const int* in_sizes, int n_in,
                              void* d_out, int out_size, void* d_ws, size_t ws_size,
                              hipStream_t stream) {
    (void)in_sizes; (void)n_in; (void)out_size; (void)ws_size;
    const float* all_span_vecs = (const float*)d_in[0];
    const float* span_vecs     = (const float*)d_in[1];
    const int*   span_begin    = (const int*)d_in[2];
    const int*   span_end      = (const int*)d_in[3];
    const float* mask          = (const float*)d_in[4];
    const float* lens          = (const float*)d_in[5];
    const int*   prune         = (const int*)d_in[6];
    const float* lw  = (const float*)d_in[7];
    const float* lb  = (const float*)d_in[8];
    const float* rw  = (const float*)d_in[9];
    const float* rb  = (const float*)d_in[10];
    const float* dist_emb = (const float*)d_in[11];
    const float* out_w    = (const float*)d_in[12];
    const float* out_b    = (const float*)d_in[13];
    const float* A_w = (const float*)d_in[14];
    const float* B_w = (const float*)d_in[15];
    const float* gw  = (const float*)d_in[16];
    const float* gb  = (const float*)d_in[17];

    float* out_all = (float*)d_out;
    float* out_upd = out_all + (size_t)B_*N_*D_;
    float* out_sc  = out_upd + (size_t)BK_*D_;

    float* ws     = (float*)d_ws;
    float* leftb  = ws;                       // BK*H fp32
    float* U0     = leftb + (size_t)BK_*H_;   // BK*D
    float* U1     = U0 + (size_t)BK_*D_;      // BK*D
    float* cbuf   = U1 + (size_t)BK_*D_;      // BK*D
    unsigned short* WAb = (unsigned short*)(cbuf + (size_t)BK_*D_);
    unsigned short* WBb = WAb + (size_t)D_*L_;
    unsigned short* lwb = WBb + (size_t)D_*L_;
    unsigned short* rwb = lwb + (size_t)H_*D_;
    unsigned short* owb = rwb + (size_t)H_*D_;
    unsigned short* gwb = owb + (size_t)L_*H_;
    unsigned short* deb = gwb + (size_t)D_*2*D_;   // 64*H bf16
    unsigned short* rbb = deb + (size_t)64*H_;     // BK*H bf16 (right proj)
    unsigned short* Ub0 = rbb + (size_t)BK_*H_;
    unsigned short* Ub1 = Ub0 + (size_t)BK_*D_;
    unsigned short* Pt  = Ub1 + (size_t)BK_*D_;    // B*K*K*L bf16

    hipMemcpyAsync(out_all, all_span_vecs, sizeof(float)*(size_t)B_*N_*D_,
                   hipMemcpyDeviceToDevice, stream);

    dim3 blk256(256), blk64(64);
    conv_all<<<dim3(2048), blk256, 0, stream>>>(lw, rw, out_w, gw, A_w, B_w, span_vecs, dist_emb,
                                                lwb, rwb, owb, gwb, WAb, WBb, Ub0, deb);
    lr_mfma<<<dim3(BK_/16, H_/64, 2), blk64, 0, stream>>>(Ub0, lwb, lb, rwb, rb, leftb, rbb);
    scores_v6<<<dim3(K_/64, K_/8, B_), blk256, 0, stream>>>(leftb, rbb, span_begin, span_end,
                                                            deb, owb, out_b, mask,
                                                            out_sc, Pt, 1);
    const float* Ucur = span_vecs;
    const unsigned short* Ubcur = Ub0;
    float* nexts[3] = {U0, U1, out_upd};
    unsigned short* nextsUb[3] = {Ub1, Ub0, Ub1};
    for (int it = 0; it < 3; ++it) {
        hipMemsetAsync(cbuf, 0, sizeof(float)*(size_t)BK_*D_, stream);
        ctxt_kernel<<<dim3(768), blk256, 0, stream>>>(Pt, Ucur, WAb, WBb, lens, cbuf);
        gate_mfma<<<dim3(BK_/16, D_/64), blk64, 0, stream>>>(Ubcur, gwb, gb,
                                                             Ucur, cbuf, nexts[it], nextsUb[it]);
        Ucur = nexts[it];
        Ubcur = nextsUb[it];
        lr_mfma<<<dim3(BK_/16, H_/64, 2), blk64, 0, stream>>>(Ubcur, lwb, lb, rwb, rb, leftb, rbb);
        scores_v6<<<dim3(K_/64, K_/8, B_), blk256, 0, stream>>>(leftb, rbb, span_begin, span_end,
                                                                deb, owb, out_b, mask,
                                                                out_sc, Pt, it == 2 ? 0 : 1);
    }
    scatter_kernel<<<dim3(BK_), blk256, 0, stream>>>(out_upd, prune, lens, out_all);
}